// Round 13
// baseline (512.469 us; speedup 1.0000x reference)
//
#include <hip/hip_runtime.h>
#include <stdint.h>

#define BT_TOK 4096
#define EDIM 768
#define FDIM 24576

// ---------- monotone float<->uint transform (order-preserving) ----------
__device__ __forceinline__ uint32_t f2u(float f) {
    uint32_t b = __float_as_uint(f);
    return (b & 0x80000000u) ? ~b : (b | 0x80000000u);
}
__device__ __forceinline__ float u2f(uint32_t u) {
    uint32_t b = (u & 0x80000000u) ? (u & 0x7FFFFFFFu) : ~u;
    return __uint_as_float(b);
}

#define GBM 128             // encode tile rows (4 waves, 2x2 wave grid)
#define GBN 128             // encode tile cols
#define NSEG (FDIM / GBN)   // 192 column-block segments per row
#define SEGW 32             // words per segment = 128 B
#define SEGCAP 15           // [0]=count, [1..15]=keys, [16..30]=idx, [31]=pad
#define SEGPRE (NSEG * SEGW) // 6144 words (MODE 0 layout)
#define ZCB (SEGPRE / GBN)   // 48 (MODE 0)
#define BANDCAP 160
#define T0 0.6f
#define DELTA2 0.035f        // i8-quant noise band: 2 x 6 sigma

typedef int   i32x4 __attribute__((ext_vector_type(4)));
typedef float f32x4 __attribute__((ext_vector_type(4)));

// ============================================================
// K0a: per-row i8 quantization of (x - b_dec): Ai8[4096][768], sxr[4096]
// ============================================================
__global__ __launch_bounds__(256)
void build_A_i8(const float* __restrict__ x, const float* __restrict__ bdec,
                unsigned char* __restrict__ Ai8, float* __restrict__ sxr)
{
    const int w = threadIdx.x >> 6, lane = threadIdx.x & 63;
    const int row = blockIdx.x * 4 + w;
    const float* src = x + (size_t)row * EDIM + lane * 12;
    const float* bd  = bdec + lane * 12;
    float d[12];
    #pragma unroll
    for (int t = 0; t < 3; ++t) {
        float4 v = *(const float4*)(src + t * 4);
        float4 b = *(const float4*)(bd + t * 4);
        d[t*4+0] = v.x - b.x; d[t*4+1] = v.y - b.y;
        d[t*4+2] = v.z - b.z; d[t*4+3] = v.w - b.w;
    }
    float m = 0.f;
    #pragma unroll
    for (int j = 0; j < 12; ++j) m = fmaxf(m, fabsf(d[j]));
    #pragma unroll
    for (int s = 1; s < 64; s <<= 1) m = fmaxf(m, __shfl_xor(m, s, 64));
    const float inv = (m > 0.f) ? 127.f / m : 0.f;
    if (lane == 0) sxr[row] = m / 127.f;
    uint32_t* po = (uint32_t*)(Ai8 + (size_t)row * EDIM) + lane * 3;
    #pragma unroll
    for (int t = 0; t < 3; ++t) {
        uint32_t pk = 0;
        #pragma unroll
        for (int j = 0; j < 4; ++j) {
            int q = (int)rintf(d[t*4+j] * inv);
            q = (q > 127) ? 127 : ((q < -127) ? -127 : q);
            pk |= ((uint32_t)(q & 255)) << (8 * j);
        }
        po[t] = pk;
    }
}

// ============================================================
// K0b: W_enc [768][24576] -> WTf fp32 [24576][768]  (transpose only)
// ============================================================
#define TT 64
__global__ __launch_bounds__(256)
void build_WT(const float* __restrict__ Wenc, float* __restrict__ WTf)
{
    __shared__ float tile[TT][TT + 4];
    const int n0 = blockIdx.x * TT, k0 = blockIdx.y * TT;
    const int t = threadIdx.x;

    const int krow = t >> 2, cseg = (t & 3) * 16;
    const float* src = Wenc + (size_t)(k0 + krow) * FDIM + n0 + cseg;
    float4 a0 = *(const float4*)(src);
    float4 a1 = *(const float4*)(src + 4);
    float4 a2 = *(const float4*)(src + 8);
    float4 a3 = *(const float4*)(src + 12);
    *(float4*)&tile[krow][cseg]      = a0;
    *(float4*)&tile[krow][cseg + 4]  = a1;
    *(float4*)&tile[krow][cseg + 8]  = a2;
    *(float4*)&tile[krow][cseg + 12] = a3;
    __syncthreads();

    const int nrow = t >> 2, kseg = (t & 3) * 16;
    float vals[16];
    #pragma unroll
    for (int i = 0; i < 16; ++i) vals[i] = tile[kseg + i][nrow];
    const size_t orow = (size_t)(n0 + nrow) * EDIM + k0 + kseg;
    #pragma unroll
    for (int i = 0; i < 16; i += 4)
        *(float4*)(WTf + orow + i) = make_float4(vals[i], vals[i+1], vals[i+2], vals[i+3]);
}

// ============================================================
// K0c: per-feature i8 quantization of W: Wi8[24576][768], sw[24576]
// ============================================================
__global__ __launch_bounds__(256)
void quantW_i8(const float* __restrict__ WTf, unsigned char* __restrict__ Wi8,
               float* __restrict__ sw)
{
    const int w = threadIdx.x >> 6, lane = threadIdx.x & 63;
    const int row = blockIdx.x * 4 + w;
    const float* src = WTf + (size_t)row * EDIM + lane * 12;
    float d[12];
    #pragma unroll
    for (int t = 0; t < 3; ++t) {
        float4 v = *(const float4*)(src + t * 4);
        d[t*4+0] = v.x; d[t*4+1] = v.y; d[t*4+2] = v.z; d[t*4+3] = v.w;
    }
    float m = 0.f;
    #pragma unroll
    for (int j = 0; j < 12; ++j) m = fmaxf(m, fabsf(d[j]));
    #pragma unroll
    for (int s = 1; s < 64; s <<= 1) m = fmaxf(m, __shfl_xor(m, s, 64));
    const float inv = (m > 0.f) ? 127.f / m : 0.f;
    if (lane == 0) sw[row] = m / 127.f;
    uint32_t* po = (uint32_t*)(Wi8 + (size_t)row * EDIM) + lane * 3;
    #pragma unroll
    for (int t = 0; t < 3; ++t) {
        uint32_t pk = 0;
        #pragma unroll
        for (int j = 0; j < 4; ++j) {
            int q = (int)rintf(d[t*4+j] * inv);
            q = (q > 127) ? 127 : ((q < -127) ? -127 : q);
            pk |= ((uint32_t)(q & 255)) << (8 * j);
        }
        po[t] = pk;
    }
}

// ============================================================
// K1: i8 MFMA encode GEMM, 128x128 tile, 4 waves, BK=192.
// MODE 1 (R13): encode writes ONLY the 16KB contiguous cand burst per
// block (~98 MB total). fm zeroing fully offloaded to hipMemsetAsync
// (fillBuffer achieves 6.7 TB/s vs our kernel's 2 TB/s store ceiling at
// 3 waves/SIMD — R12 postmortem). MODE 0 keeps the self-zeroing layout.
// ============================================================
__device__ __forceinline__ void gld16(const unsigned char* g, void* l) {
    __builtin_amdgcn_global_load_lds(
        (const __attribute__((address_space(1))) void*)g,
        (__attribute__((address_space(3))) void*)l, 16, 0, 0);
}

template<int MODE>
__global__ __launch_bounds__(256)
void encode_i8_cand(const unsigned char* __restrict__ A,   // [4096][768] i8
                    const unsigned char* __restrict__ BT,  // [24576][768] i8
                    const float* __restrict__ benc,
                    const float* __restrict__ sxr,         // [4096]
                    const float* __restrict__ sw,          // [24576]
                    float* __restrict__ fm,
                    uint32_t* __restrict__ cand)           // MODE1: [192][4096][32]
{
    __shared__ int As_i[3 * 2048];   // 24 KB staging; MODE1 epilogue aliases 16 KB
    __shared__ int Bs_i[3 * 2048];   // 24 KB
    __shared__ int rowcnt[GBM];

    const int tid = threadIdx.x;
    const int l = tid & 63, w = tid >> 6;              // 4 waves
    const int wrow = (w >> 1) * 64, wcol = (w & 1) * 64;   // 2x2 wave grid
    const int lr = l & 15, lg = l >> 4;
    const int bm = blockIdx.y * GBM, bn = blockIdx.x * GBN;
    const int cb = blockIdx.x;

    // ---- staging addresses: linear idx -> (kgroup, row); dest = idx*16B ----
    const int r0 = tid & 127, g0 = tid >> 7;
    const unsigned char* gA0 = A  + (size_t)(bm + r0) * EDIM + g0 * 16;
    const unsigned char* gA1 = A  + (size_t)(bm + r0) * EDIM + (g0 + 2) * 16;
    const unsigned char* gB0 = BT + (size_t)(bn + r0) * EDIM + g0 * 16;
    const unsigned char* gB1 = BT + (size_t)(bn + r0) * EDIM + (g0 + 2) * 16;
    int* lA0 = As_i + tid * 4;
    int* lA1 = As_i + (tid + 256) * 4;
    int* lB0 = Bs_i + tid * 4;
    int* lB1 = Bs_i + (tid + 256) * 4;

    i32x4 acc[4][4];
    #pragma unroll
    for (int i = 0; i < 4; ++i)
        #pragma unroll
        for (int j = 0; j < 4; ++j)
            acc[i][j] = (i32x4){0, 0, 0, 0};

    for (int st = 0; st < 4; ++st) {                   // 4 stage groups x BK=192
        __syncthreads();
        #pragma unroll
        for (int t = 0; t < 3; ++t) {
            const int kt = st * 3 + t;
            gld16(gA0 + kt * 64, lA0 + t * 2048);
            gld16(gA1 + kt * 64, lA1 + t * 2048);
            gld16(gB0 + kt * 64, lB0 + t * 2048);
            gld16(gB1 + kt * 64, lB1 + t * 2048);
        }
        __syncthreads();

        #pragma unroll
        for (int t = 0; t < 3; ++t) {
            i32x4 af[4], bfr[4];
            #pragma unroll
            for (int f = 0; f < 4; ++f) {
                af[f]  = *(const i32x4*)&As_i[t * 2048 + (lg * 128 + wrow + f * 16 + lr) * 4];
                bfr[f] = *(const i32x4*)&Bs_i[t * 2048 + (lg * 128 + wcol + f * 16 + lr) * 4];
            }
            #pragma unroll
            for (int fi = 0; fi < 4; ++fi)
                #pragma unroll
                for (int fj = 0; fj < 4; ++fj)
                    acc[fi][fj] = __builtin_amdgcn_mfma_i32_16x16x64_i8(
                        af[fi], bfr[fj], acc[fi][fj], 0, 0, 0);
        }
    }

    float bev[4], swv[4];
    #pragma unroll
    for (int fj = 0; fj < 4; ++fj) {
        const int c = bn + wcol + fj * 16 + lr;
        bev[fj] = benc[c];
        swv[fj] = sw[c];
    }

    if (MODE == 1) {
        // -------- epilogue: compose 128 segment lines in LDS, stream 16 KB --------
        uint32_t* lseg = (uint32_t*)As_i;   // 16 KB of staging reuse
        __syncthreads();                    // all MFMA LDS reads done
        for (int i = tid; i < 4096; i += 256) lseg[i] = 0u;
        if (tid < GBM) rowcnt[tid] = 0;
        __syncthreads();

        #pragma unroll
        for (int fi = 0; fi < 4; ++fi) {
            #pragma unroll
            for (int q = 0; q < 4; ++q) {
                const int rl = wrow + fi * 16 + lg * 4 + q;
                const float srow = sxr[bm + rl];
                #pragma unroll
                for (int fj = 0; fj < 4; ++fj) {
                    const float v = (float)acc[fi][fj][q] * (srow * swv[fj]) + bev[fj];
                    if (v > T0) {
                        const int c = bn + wcol + fj * 16 + lr;
                        int p = atomicAdd(&rowcnt[rl], 1);
                        if (p < SEGCAP) {
                            lseg[rl * SEGW + 1 + p] = f2u(v);
                            lseg[rl * SEGW + 1 + SEGCAP + p] = (uint32_t)c;
                        }
                    }
                }
            }
        }
        __syncthreads();
        if (tid < GBM) lseg[tid * SEGW] = (uint32_t)rowcnt[tid];
        __syncthreads();
        // contiguous 16 KB burst: cand[(cb*4096 + bm) .. +128 rows][32w]
        int4* dst = (int4*)(cand + ((size_t)cb * BT_TOK + bm) * SEGW);
        const int4* srcl = (const int4*)lseg;
        #pragma unroll
        for (int i = 0; i < 4; ++i) dst[tid + i * 256] = srcl[tid + i * 256];
    } else {
        // -------- MODE 0: strided 128B lines in fm prefix + strided zeros --------
        for (int i = tid; i < GBM; i += 256) rowcnt[i] = 0;
        __syncthreads();
        #pragma unroll
        for (int fi = 0; fi < 4; ++fi) {
            #pragma unroll
            for (int q = 0; q < 4; ++q) {
                const int rl = wrow + fi * 16 + lg * 4 + q;
                const float srow = sxr[bm + rl];
                uint32_t* seg = (uint32_t*)(fm + (size_t)(bm + rl) * FDIM) + (size_t)cb * SEGW;
                #pragma unroll
                for (int fj = 0; fj < 4; ++fj) {
                    const float v = (float)acc[fi][fj][q] * (srow * swv[fj]) + bev[fj];
                    if (v > T0) {
                        const int c = bn + wcol + fj * 16 + lr;
                        int p = atomicAdd(&rowcnt[rl], 1);
                        if (p < SEGCAP) {
                            seg[1 + p] = f2u(v);
                            seg[1 + SEGCAP + p] = (uint32_t)c;
                        }
                    }
                }
            }
        }
        __syncthreads();
        for (int i = tid; i < GBM; i += 256) {
            uint32_t* seg = (uint32_t*)(fm + (size_t)(bm + i) * FDIM) + (size_t)cb * SEGW;
            seg[0] = (uint32_t)rowcnt[i];
        }
        if (cb >= ZCB) {
            const float4 z4 = make_float4(0.f, 0.f, 0.f, 0.f);
            const int rz = tid >> 5, cz = (tid & 31) * 4;
            #pragma unroll
            for (int p = 0; p < 16; ++p)
                *(float4*)(fm + (size_t)(bm + p * 8 + rz) * FDIM + bn + cz) = z4;
        }
    }
}

// ============================================================
// bitonic sort on 512-entry LDS arrays: desc by key, tie asc idx
// ============================================================
__device__ __forceinline__ void sort512(uint32_t* ckey, uint32_t* cidx, int tid) {
    for (int ksz = 2; ksz <= 512; ksz <<= 1) {
        for (int j = ksz >> 1; j > 0; j >>= 1) {
            for (int i = tid; i < 512; i += 256) {
                const int ixj = i ^ j;
                if (ixj > i) {
                    uint32_t ka = ckey[i], kb = ckey[ixj];
                    uint32_t ia = cidx[i], ib = cidx[ixj];
                    bool after = (ka < kb) || (ka == kb && ia > ib);
                    bool descBlock = ((i & ksz) == 0);
                    if (descBlock ? after : !after) {
                        ckey[i] = kb; ckey[ixj] = ka;
                        cidx[i] = ib; cidx[ixj] = ia;
                    }
                }
            }
            __syncthreads();
        }
    }
}

// ============================================================
// K2: gather segments -> [MODE0: zero prefix] -> sort -> fp64 band refine
// -> exact top-k -> scatter, decode. Fallback: coalesced dense recompute.
// MODE1: fm row arrives fully zeroed (hipMemsetAsync before encode).
// ============================================================
template<int MODE>
__global__ __launch_bounds__(256)
void topk2(float* __restrict__ fm, float* __restrict__ xrec,
           const float* __restrict__ x, const float* __restrict__ WTf,
           const float* __restrict__ Wenc, const float* __restrict__ Wdec,
           const float* __restrict__ benc, const float* __restrict__ bdec,
           const int* __restrict__ kptr, const uint32_t* __restrict__ cand)
{
    const int row = blockIdx.x;
    const int tid = threadIdx.x;
    float* lrow = fm + (size_t)row * FDIM;
    const uint32_t* lrowu = (const uint32_t*)lrow;
    const float* xr = x + (size_t)row * EDIM;
    int kk = *kptr;
    if (kk < 1) kk = 1;
    if (kk > 511) kk = 511;

    __shared__ uint32_t ckey[512];
    __shared__ uint32_t cidx[512];
    __shared__ int      segc[NSEG];
    __shared__ int      scan[256];
    __shared__ double   exd[BANDCAP];
    __shared__ int      ssel[BANDCAP];
    __shared__ int      slist[BANDCAP];
    __shared__ int      redi[256];
    __shared__ float    xd[EDIM];
    __shared__ int      badf, cc;

    // ---- read per-segment counts, detect overflow ----
    if (tid == 0) badf = 0;
    __syncthreads();
    for (int s = tid; s < NSEG; s += 256) {
        const int c = (MODE == 0)
            ? (int)lrowu[(size_t)s * SEGW]
            : (int)cand[((size_t)s * BT_TOK + row) * SEGW];
        segc[s] = c;
        if (c > SEGCAP || c < 0) atomicOr(&badf, 1);
    }
    __syncthreads();

    // ---- inclusive prefix sum over segment counts ----
    scan[tid] = (tid < NSEG) ? segc[tid] : 0;
    __syncthreads();
    for (int d = 1; d < 256; d <<= 1) {
        int v = (tid >= d) ? scan[tid - d] : 0;
        __syncthreads();
        scan[tid] += v;
        __syncthreads();
    }
    const int total = scan[NSEG - 1];

    bool fb = (badf != 0) || (total < kk) || (total > 512) || (kk > BANDCAP);
    float t32 = 0.f;

    if (!fb) {
        // ---- gather segment entries into compact LDS list ----
        for (int t = tid; t < NSEG * SEGCAP; t += 256) {
            const int s = t / SEGCAP, sl = t - s * SEGCAP;
            if (sl < segc[s]) {
                const int pos = scan[s] - segc[s] + sl;
                if (MODE == 0) {
                    ckey[pos] = lrowu[(size_t)s * SEGW + 1 + sl];
                    cidx[pos] = lrowu[(size_t)s * SEGW + 1 + SEGCAP + sl];
                } else {
                    const size_t b = ((size_t)s * BT_TOK + row) * SEGW;
                    ckey[pos] = cand[b + 1 + sl];
                    cidx[pos] = cand[b + 1 + SEGCAP + sl];
                }
            }
        }
        for (int i = total + tid; i < 512; i += 256) { ckey[i] = 0u; cidx[i] = 0u; }
        __syncthreads();
        if (MODE == 0) {
            const float4 z4 = make_float4(0.f, 0.f, 0.f, 0.f);
            for (int i = tid * 4; i < SEGPRE; i += 1024) *(float4*)(lrow + i) = z4;
        }
        sort512(ckey, cidx, tid);
        t32 = u2f(ckey[kk - 1]);
        if (!(t32 - DELTA2 > T0)) fb = true;
    }

    int nb = 0;
    if (!fb) {
        const float blo = t32 - DELTA2;
        int lm = 0;
        for (int j = tid; j < total; j += 256) lm += (u2f(ckey[j]) >= blo) ? 1 : 0;
        redi[tid] = lm;
        __syncthreads();
        for (int s = 128; s > 0; s >>= 1) { if (tid < s) redi[tid] += redi[tid + s]; __syncthreads(); }
        nb = redi[0];
        if (nb > BANDCAP) fb = true;
        __syncthreads();
    }

    const int e0 = tid, e1 = tid + 256, e2 = tid + 512;

    if (fb) {
        // ---------- FALLBACK (rare): coalesced dense fp32 recompute ----------
        for (int e = tid; e < EDIM; e += 256) xd[e] = xr[e] - bdec[e];
        __syncthreads();
        for (int f0 = 0; f0 < FDIM; f0 += 256) {
            const int f = f0 + tid;
            float a0 = 0.f, a1 = 0.f, a2 = 0.f, a3 = 0.f;
            const float* wp = Wenc + f;
            #pragma unroll 4
            for (int e = 0; e < EDIM; e += 4) {
                a0 = fmaf(xd[e + 0], wp[(size_t)(e + 0) * FDIM], a0);
                a1 = fmaf(xd[e + 1], wp[(size_t)(e + 1) * FDIM], a1);
                a2 = fmaf(xd[e + 2], wp[(size_t)(e + 2) * FDIM], a2);
                a3 = fmaf(xd[e + 3], wp[(size_t)(e + 3) * FDIM], a3);
            }
            lrow[f] = (a0 + a1) + (a2 + a3) + benc[f];
        }
        __syncthreads();

        uint32_t ulo = 0u, uhi = 0xFFFFFFFFu, ut = f2u(T0);
        int state = 0; uint32_t kthu = 0u; int cfound = 0;
        for (int it = 0; it < 72; ++it) {
            if (uhi - ulo <= 1u) { state = 2; kthu = uhi; break; }
            if (ut <= ulo) ut = ulo + 1u;
            if (ut >= uhi) ut = uhi - 1u;
            const float t = u2f(ut);
            __syncthreads();
            if (tid == 0) cc = 0;
            __syncthreads();
            for (int i = tid * 4; i < FDIM; i += 1024) {
                float4 v = *(const float4*)(lrow + i);
                float vv[4] = {v.x, v.y, v.z, v.w};
                #pragma unroll
                for (int j = 0; j < 4; ++j) {
                    if (vv[j] > t) {
                        int p = atomicAdd(&cc, 1);
                        if (p < 512) { ckey[p] = f2u(vv[j]); cidx[p] = (uint32_t)(i + j); }
                    }
                }
            }
            __syncthreads();
            const int c = cc;
            if (c >= kk && c <= 512) { state = 1; cfound = c; break; }
            if (c < kk) uhi = ut; else ulo = ut;
            ut = ulo + ((uhi - ulo) >> 1);
        }
        if (state == 0) { state = 2; kthu = uhi; }

        if (state == 1) {
            for (int i = cfound + tid; i < 512; i += 256) { ckey[i] = 0u; cidx[i] = 0u; }
            __syncthreads();
            sort512(ckey, cidx, tid);
            const float kthf = u2f(ckey[kk - 1]);
            int lm = 0;
            for (int j = tid; j < cfound; j += 256) lm += (u2f(ckey[j]) >= kthf) ? 1 : 0;
            redi[tid] = lm;
            __syncthreads();
            for (int s = 128; s > 0; s >>= 1) { if (tid < s) redi[tid] += redi[tid + s]; __syncthreads(); }
            const int m = redi[0];

            const float4 z4 = make_float4(0.f, 0.f, 0.f, 0.f);
            for (int i = tid * 4; i < FDIM; i += 1024) *(float4*)(lrow + i) = z4;
            __syncthreads();
            for (int j = tid; j < m; j += 256) lrow[cidx[j]] = u2f(ckey[j]);

            float a0 = 0.f, a1 = 0.f, a2 = 0.f;
            for (int j = 0; j < m; ++j) {
                const float v = u2f(ckey[j]);
                const float* wr = Wdec + (size_t)cidx[j] * EDIM;
                a0 = fmaf(v, wr[e0], a0);
                a1 = fmaf(v, wr[e1], a1);
                a2 = fmaf(v, wr[e2], a2);
            }
            xrec[(size_t)row * EDIM + e0] = a0 + bdec[e0];
            xrec[(size_t)row * EDIM + e1] = a1 + bdec[e1];
            xrec[(size_t)row * EDIM + e2] = a2 + bdec[e2];
        } else {
            const float kthf = u2f(kthu);
            float a0 = 0.f, a1 = 0.f, a2 = 0.f;
            for (int basei = 0; basei < FDIM; basei += 512) {
                __syncthreads();
                if (tid == 0) cc = 0;
                __syncthreads();
                const int i = basei + tid * 2;
                float2 v = *(const float2*)(lrow + i);
                float2 o;
                o.x = (v.x >= kthf) ? v.x : 0.f;
                o.y = (v.y >= kthf) ? v.y : 0.f;
                *(float2*)(lrow + i) = o;
                if (v.x >= kthf) { int p = atomicAdd(&cc, 1); ckey[p] = __float_as_uint(v.x); cidx[p] = (uint32_t)i; }
                if (v.y >= kthf) { int p = atomicAdd(&cc, 1); ckey[p] = __float_as_uint(v.y); cidx[p] = (uint32_t)(i + 1); }
                __syncthreads();
                const int c = cc;
                for (int j = 0; j < c; ++j) {
                    const float v2 = __uint_as_float(ckey[j]);
                    const float* wr = Wdec + (size_t)cidx[j] * EDIM;
                    a0 = fmaf(v2, wr[e0], a0);
                    a1 = fmaf(v2, wr[e1], a1);
                    a2 = fmaf(v2, wr[e2], a2);
                }
            }
            xrec[(size_t)row * EDIM + e0] = a0 + bdec[e0];
            xrec[(size_t)row * EDIM + e1] = a1 + bdec[e1];
            xrec[(size_t)row * EDIM + e2] = a2 + bdec[e2];
        }
        return;
    }

    // ---------- MAIN PATH ----------
    const int wv = tid >> 6, ln = tid & 63;
    for (int j = wv; j < nb; j += 4) {
        const float* wt = WTf + (size_t)cidx[j] * EDIM;
        double a0d = 0.0, a1d = 0.0, a2d = 0.0;
        {
            const int ea = ln, eb = ln + 256, ec = ln + 512;
            #pragma unroll
            for (int i = 0; i < 4; ++i) {
                a0d += ((double)xr[ea + i * 64] - (double)bdec[ea + i * 64]) * (double)wt[ea + i * 64];
                a1d += ((double)xr[eb + i * 64] - (double)bdec[eb + i * 64]) * (double)wt[eb + i * 64];
                a2d += ((double)xr[ec + i * 64] - (double)bdec[ec + i * 64]) * (double)wt[ec + i * 64];
            }
        }
        double a = a0d + a1d + a2d;
        #pragma unroll
        for (int s = 32; s > 0; s >>= 1) a += __shfl_down(a, s, 64);
        if (ln == 0) exd[j] = a + (double)benc[cidx[j]];
    }
    __syncthreads();

    // exact rank selection: top kk by (value desc, idx asc, pos asc)
    for (int j = tid; j < nb; j += 256) {
        const double vj = exd[j];
        const uint32_t ij = cidx[j];
        int rank = 0;
        for (int i = 0; i < nb; ++i) {
            const double vi = exd[i];
            rank += (vi > vj || (vi == vj && (cidx[i] < ij || (cidx[i] == ij && i < j)))) ? 1 : 0;
        }
        ssel[j] = (rank < kk) ? 1 : 0;
    }
    __syncthreads();

    // selected list ordered by feature idx (deterministic decode order)
    for (int j = tid; j < nb; j += 256) {
        if (ssel[j]) {
            const uint32_t ij = cidx[j];
            int pos = 0;
            for (int i = 0; i < nb; ++i)
                pos += (ssel[i] && (cidx[i] < ij || (cidx[i] == ij && i < j))) ? 1 : 0;
            slist[pos] = j;
        }
    }
    __syncthreads();

    // scatter EXACT values into the pre-zeroed fm row
    for (int j = tid; j < kk; j += 256) {
        const int q = slist[j];
        lrow[cidx[q]] = (float)exd[q];
    }

    // decode with exact values
    float a0 = 0.f, a1 = 0.f, a2 = 0.f;
    for (int j = 0; j < kk; ++j) {
        const int q = slist[j];
        const float v = (float)exd[q];
        const float* wr = Wdec + (size_t)cidx[q] * EDIM;
        a0 = fmaf(v, wr[e0], a0);
        a1 = fmaf(v, wr[e1], a1);
        a2 = fmaf(v, wr[e2], a2);
    }
    xrec[(size_t)row * EDIM + e0] = a0 + bdec[e0];
    xrec[(size_t)row * EDIM + e1] = a1 + bdec[e1];
    xrec[(size_t)row * EDIM + e2] = a2 + bdec[e2];
}

// ============================================================
// FALLBACK PATH (ws too small): round-1 fp32 kernels, verbatim
// ============================================================
#define BM 128
#define BN 128
#define BKK 8
#define CAP 512

__global__ __launch_bounds__(256)
void encode_gemm(const float* __restrict__ x, const float* __restrict__ Wenc,
                 const float* __restrict__ benc, const float* __restrict__ bdec,
                 float* __restrict__ lat)
{
    __shared__ float Asf[BKK][BM];
    __shared__ float Bsf[BKK][BN];

    const int tid = threadIdx.x;
    const int tx = tid & 15, ty = tid >> 4;
    const int bm = blockIdx.y * BM;
    const int bn = blockIdx.x * BN;

    const int arow = tid >> 1, ac4 = (tid & 1) * 4;
    const int bkr  = tid >> 5, bc4 = (tid & 31) * 4;

    float acc[8][8] = {};
    float af[8], bf[8];

    for (int k0 = 0; k0 < EDIM; k0 += BKK) {
        float4 av = *(const float4*)(x + (size_t)(bm + arow) * EDIM + k0 + ac4);
        float4 bd = *(const float4*)(bdec + k0 + ac4);
        av.x -= bd.x; av.y -= bd.y; av.z -= bd.z; av.w -= bd.w;
        float4 bv = *(const float4*)(Wenc + (size_t)(k0 + bkr) * FDIM + bn + bc4);
        __syncthreads();
        Asf[ac4 + 0][arow] = av.x; Asf[ac4 + 1][arow] = av.y;
        Asf[ac4 + 2][arow] = av.z; Asf[ac4 + 3][arow] = av.w;
        *(float4*)&Bsf[bkr][bc4] = bv;
        __syncthreads();
        #pragma unroll
        for (int kkk = 0; kkk < BKK; ++kkk) {
            *(float4*)&af[0] = *(const float4*)&Asf[kkk][ty * 8];
            *(float4*)&af[4] = *(const float4*)&Asf[kkk][ty * 8 + 4];
            *(float4*)&bf[0] = *(const float4*)&Bsf[kkk][tx * 8];
            *(float4*)&bf[4] = *(const float4*)&Bsf[kkk][tx * 8 + 4];
            #pragma unroll
            for (int i = 0; i < 8; ++i)
                #pragma unroll
                for (int j = 0; j < 8; ++j)
                    acc[i][j] = fmaf(af[i], bf[j], acc[i][j]);
        }
    }

    float4 be0 = *(const float4*)(benc + bn + tx * 8);
    float4 be1 = *(const float4*)(benc + bn + tx * 8 + 4);
    #pragma unroll
    for (int i = 0; i < 8; ++i) {
        size_t ro = (size_t)(bm + ty * 8 + i) * FDIM + bn + tx * 8;
        float4 o0 = make_float4(acc[i][0] + be0.x, acc[i][1] + be0.y,
                                acc[i][2] + be0.z, acc[i][3] + be0.w);
        float4 o1 = make_float4(acc[i][4] + be1.x, acc[i][5] + be1.y,
                                acc[i][6] + be1.z, acc[i][7] + be1.w);
        *(float4*)(lat + ro)     = o0;
        *(float4*)(lat + ro + 4) = o1;
    }
}

__global__ __launch_bounds__(256)
void topk_mask_decode(float* __restrict__ lat, const float* __restrict__ Wdec,
                      const float* __restrict__ bdec, const int* __restrict__ kptr,
                      float* __restrict__ xrec)
{
    const int row = blockIdx.x;
    const int tid = threadIdx.x;
    float* lrow = lat + (size_t)row * FDIM;
    int kk = *kptr;
    if (kk < 1) kk = 1;
    if (kk > CAP) kk = CAP;

    __shared__ uint32_t ckey[CAP];
    __shared__ uint32_t cidx[CAP];
    __shared__ float redf[256];
    __shared__ int   redi[256];
    __shared__ int   cc;

    float ss = 0.f;
    for (int i = tid * 4; i < FDIM; i += 1024) {
        float4 v = *(const float4*)(lrow + i);
        ss = fmaf(v.x, v.x, fmaf(v.y, v.y, fmaf(v.z, v.z, fmaf(v.w, v.w, ss))));
    }
    redf[tid] = ss;
    __syncthreads();
    for (int s = 128; s > 0; s >>= 1) { if (tid < s) redf[tid] += redf[tid + s]; __syncthreads(); }
    const float sigma = sqrtf(redf[0] / (float)FDIM);

    uint32_t ulo = 0u, uhi = 0xFFFFFFFFu;
    uint32_t ut = f2u(2.7f * sigma);
    int state = 0; uint32_t kthu = 0u; int cfound = 0;

    for (int it = 0; it < 72; ++it) {
        if (uhi - ulo <= 1u) { state = 2; kthu = uhi; break; }
        if (ut <= ulo) ut = ulo + 1u;
        if (ut >= uhi) ut = uhi - 1u;
        const float t = u2f(ut);
        __syncthreads();
        if (tid == 0) cc = 0;
        __syncthreads();
        for (int i = tid * 4; i < FDIM; i += 1024) {
            float4 v = *(const float4*)(lrow + i);
            float vv[4] = {v.x, v.y, v.z, v.w};
            #pragma unroll
            for (int j = 0; j < 4; ++j) {
                if (vv[j] > t) {
                    int p = atomicAdd(&cc, 1);
                    if (p < CAP) { ckey[p] = f2u(vv[j]); cidx[p] = (uint32_t)(i + j); }
                }
            }
        }
        __syncthreads();
        const int c = cc;
        if (c >= kk && c <= CAP) { state = 1; cfound = c; break; }
        if (c < kk) uhi = ut; else ulo = ut;
        ut = ulo + ((uhi - ulo) >> 1);
    }
    if (state == 0) { state = 2; kthu = uhi; }

    const int e0 = tid, e1 = tid + 256, e2 = tid + 512;

    if (state == 1) {
        for (int i = cfound + tid; i < CAP; i += 256) { ckey[i] = 0u; cidx[i] = 0u; }
        __syncthreads();
        for (int ksz = 2; ksz <= CAP; ksz <<= 1) {
            for (int j = ksz >> 1; j > 0; j >>= 1) {
                for (int i = tid; i < CAP; i += 256) {
                    const int ixj = i ^ j;
                    if (ixj > i) {
                        uint32_t ka = ckey[i], kb = ckey[ixj];
                        uint32_t ia = cidx[i], ib = cidx[ixj];
                        bool after = (ka < kb) || (ka == kb && ia > ib);
                        bool descBlock = ((i & ksz) == 0);
                        if (descBlock ? after : !after) {
                            ckey[i] = kb; ckey[ixj] = ka;
                            cidx[i] = ib; cidx[ixj] = ia;
                        }
                    }
                }
                __syncthreads();
            }
        }
        const float kthf = u2f(ckey[kk - 1]);

        int lm = 0;
        for (int j2 = tid; j2 < cfound; j2 += 256) lm += (u2f(ckey[j2]) >= kthf) ? 1 : 0;
        redi[tid] = lm;
        __syncthreads();
        for (int s = 128; s > 0; s >>= 1) { if (tid < s) redi[tid] += redi[tid + s]; __syncthreads(); }
        const int m = redi[0];

        const float4 z4 = make_float4(0.f, 0.f, 0.f, 0.f);
        for (int i = tid * 4; i < FDIM; i += 1024) *(float4*)(lrow + i) = z4;
        __syncthreads();
        for (int j2 = tid; j2 < m; j2 += 256) lrow[cidx[j2]] = u2f(ckey[j2]);

        float a0 = 0.f, a1 = 0.f, a2 = 0.f;
        for (int j2 = 0; j2 < m; ++j2) {
            const float v = u2f(ckey[j2]);
            const float* wr = Wdec + (size_t)cidx[j2] * EDIM;
            a0 = fmaf(v, wr[e0], a0);
            a1 = fmaf(v, wr[e1], a1);
            a2 = fmaf(v, wr[e2], a2);
        }
        xrec[(size_t)row * EDIM + e0] = a0 + bdec[e0];
        xrec[(size_t)row * EDIM + e1] = a1 + bdec[e1];
        xrec[(size_t)row * EDIM + e2] = a2 + bdec[e2];
    } else {
        const float kthf = u2f(kthu);
        float a0 = 0.f, a1 = 0.f, a2 = 0.f;
        for (int base = 0; base < FDIM; base += 512) {
            __syncthreads();
            if (tid == 0) cc = 0;
            __syncthreads();
            const int i = base + tid * 2;
            float2 v = *(const float2*)(lrow + i);
            float2 o;
            o.x = (v.x >= kthf) ? v.x : 0.f;
            o.y = (v.y >= kthf) ? v.y : 0.f;
            *(float2*)(lrow + i) = o;
            if (v.x >= kthf) { int p = atomicAdd(&cc, 1); ckey[p] = __float_as_uint(v.x); cidx[p] = (uint32_t)i; }
            if (v.y >= kthf) { int p = atomicAdd(&cc, 1); ckey[p] = __float_as_uint(v.y); cidx[p] = (uint32_t)(i + 1); }
            __syncthreads();
            const int c = cc;
            for (int j2 = 0; j2 < c; ++j2) {
                const float v2 = __uint_as_float(ckey[j2]);
                const float* wr = Wdec + (size_t)cidx[j2] * EDIM;
                a0 = fmaf(v2, wr[e0], a0);
                a1 = fmaf(v2, wr[e1], a1);
                a2 = fmaf(v2, wr[e2], a2);
            }
        }
        xrec[(size_t)row * EDIM + e0] = a0 + bdec[e0];
        xrec[(size_t)row * EDIM + e1] = a1 + bdec[e1];
        xrec[(size_t)row * EDIM + e2] = a2 + bdec[e2];
    }
}

// ============================================================
extern "C" void kernel_launch(void* const* d_in, const int* in_sizes, int n_in,
                              void* d_out, int out_size, void* d_ws, size_t ws_size,
                              hipStream_t stream) {
    const float* x    = (const float*)d_in[0];
    const float* Wenc = (const float*)d_in[1];
    const float* Wdec = (const float*)d_in[2];
    const float* benc = (const float*)d_in[3];
    const float* bdec = (const float*)d_in[4];
    const int*   kptr = (const int*)d_in[5];

    float* xrec = (float*)d_out;                          // (4096, 768)
    float* fm   = (float*)d_out + (size_t)BT_TOK * EDIM;  // (4096, 24576)

    const size_t szAi = (size_t)BT_TOK * EDIM;            //  3,145,728 (i8)
    const size_t szWi = (size_t)FDIM * EDIM;              // 18,874,368 (i8)
    const size_t szWT = (size_t)FDIM * EDIM * 4;          // 75,497,472 (f32)
    const size_t szSx = (size_t)BT_TOK * 4;
    const size_t szSw = (size_t)FDIM * 4;
    const size_t base = szAi + szWi + szWT + szSx + szSw;
    const size_t szCd = (size_t)NSEG * BT_TOK * SEGW * 4; // 100,663,296

    if (ws_size >= base) {
        unsigned char* Ai8 = (unsigned char*)d_ws;
        unsigned char* Wi8 = (unsigned char*)d_ws + szAi;
        float*         WTf = (float*)((char*)d_ws + szAi + szWi);
        float*         sxr = (float*)((char*)d_ws + szAi + szWi + szWT);
        float*         sw  = (float*)((char*)d_ws + szAi + szWi + szWT + szSx);
        uint32_t*      cnd = (uint32_t*)((char*)d_ws + base);

        build_A_i8<<<BT_TOK / 4, 256, 0, stream>>>(x, bdec, Ai8, sxr);
        build_WT<<<dim3(FDIM / TT, EDIM / TT), 256, 0, stream>>>(Wenc, WTf);
        quantW_i8<<<FDIM / 4, 256, 0, stream>>>(WTf, Wi8, sw);
        if (ws_size >= base + szCd) {
            // fm zeroed by fillBuffer (6.7 TB/s measured) — encode writes cand only
            hipMemsetAsync(fm, 0, (size_t)BT_TOK * FDIM * sizeof(float), stream);
            encode_i8_cand<1><<<dim3(FDIM / GBN, BT_TOK / GBM), 256, 0, stream>>>(
                Ai8, Wi8, benc, sxr, sw, fm, cnd);
            topk2<1><<<BT_TOK, 256, 0, stream>>>(fm, xrec, x, WTf, Wenc, Wdec,
                                                 benc, bdec, kptr, cnd);
        } else {
            encode_i8_cand<0><<<dim3(FDIM / GBN, BT_TOK / GBM), 256, 0, stream>>>(
                Ai8, Wi8, benc, sxr, sw, fm, nullptr);
            topk2<0><<<BT_TOK, 256, 0, stream>>>(fm, xrec, x, WTf, Wenc, Wdec,
                                                 benc, bdec, kptr, nullptr);
        }
    } else {
        dim3 g1(FDIM / BN, BT_TOK / BM);
        encode_gemm<<<g1, 256, 0, stream>>>(x, Wenc, benc, bdec, fm);
        topk_mask_decode<<<BT_TOK, 256, 0, stream>>>(fm, Wdec, bdec, kptr, xrec);
    }
}

// Round 15
// 481.039 us; speedup vs baseline: 1.0653x; 1.0653x over previous
//
#include <hip/hip_runtime.h>
#include <stdint.h>

#define BT_TOK 4096
#define EDIM 768
#define FDIM 24576

// ---------- monotone float<->uint transform (order-preserving) ----------
__device__ __forceinline__ uint32_t f2u(float f) {
    uint32_t b = __float_as_uint(f);
    return (b & 0x80000000u) ? ~b : (b | 0x80000000u);
}
__device__ __forceinline__ float u2f(uint32_t u) {
    uint32_t b = (u & 0x80000000u) ? (u & 0x7FFFFFFFu) : ~u;
    return __uint_as_float(b);
}

#define GBM 128             // encode tile rows (4 waves, 2x2 wave grid)
#define GBN 128             // encode tile cols
#define NSEG (FDIM / GBN)   // 192 column-block segments per row
#define SEGW 32             // words per segment = 128 B
#define SEGCAP 15           // [0]=count, [1..15]=keys, [16..30]=idx, [31]=pad
#define SEGPRE (NSEG * SEGW) // 6144 words (MODE 0 layout)
#define ZCB (SEGPRE / GBN)   // 48 (MODE 0)
#define BANDCAP 160
#define T0 0.6f
#define DELTA2 0.035f        // i8-quant noise band: 2 x 6 sigma

typedef int   i32x4 __attribute__((ext_vector_type(4)));
typedef float f32x4 __attribute__((ext_vector_type(4)));

// ============================================================
// K0a: per-row i8 quantization of (x - b_dec): Ai8[4096][768], sxr[4096]
// ============================================================
__global__ __launch_bounds__(256)
void build_A_i8(const float* __restrict__ x, const float* __restrict__ bdec,
                unsigned char* __restrict__ Ai8, float* __restrict__ sxr)
{
    const int w = threadIdx.x >> 6, lane = threadIdx.x & 63;
    const int row = blockIdx.x * 4 + w;
    const float* src = x + (size_t)row * EDIM + lane * 12;
    const float* bd  = bdec + lane * 12;
    float d[12];
    #pragma unroll
    for (int t = 0; t < 3; ++t) {
        float4 v = *(const float4*)(src + t * 4);
        float4 b = *(const float4*)(bd + t * 4);
        d[t*4+0] = v.x - b.x; d[t*4+1] = v.y - b.y;
        d[t*4+2] = v.z - b.z; d[t*4+3] = v.w - b.w;
    }
    float m = 0.f;
    #pragma unroll
    for (int j = 0; j < 12; ++j) m = fmaxf(m, fabsf(d[j]));
    #pragma unroll
    for (int s = 1; s < 64; s <<= 1) m = fmaxf(m, __shfl_xor(m, s, 64));
    const float inv = (m > 0.f) ? 127.f / m : 0.f;
    if (lane == 0) sxr[row] = m / 127.f;
    uint32_t* po = (uint32_t*)(Ai8 + (size_t)row * EDIM) + lane * 3;
    #pragma unroll
    for (int t = 0; t < 3; ++t) {
        uint32_t pk = 0;
        #pragma unroll
        for (int j = 0; j < 4; ++j) {
            int q = (int)rintf(d[t*4+j] * inv);
            q = (q > 127) ? 127 : ((q < -127) ? -127 : q);
            pk |= ((uint32_t)(q & 255)) << (8 * j);
        }
        po[t] = pk;
    }
}

// ============================================================
// K0b: W_enc [768][24576] -> WTf fp32 [24576][768]  (transpose only)
// ============================================================
#define TT 64
__global__ __launch_bounds__(256)
void build_WT(const float* __restrict__ Wenc, float* __restrict__ WTf)
{
    __shared__ float tile[TT][TT + 4];
    const int n0 = blockIdx.x * TT, k0 = blockIdx.y * TT;
    const int t = threadIdx.x;

    const int krow = t >> 2, cseg = (t & 3) * 16;
    const float* src = Wenc + (size_t)(k0 + krow) * FDIM + n0 + cseg;
    float4 a0 = *(const float4*)(src);
    float4 a1 = *(const float4*)(src + 4);
    float4 a2 = *(const float4*)(src + 8);
    float4 a3 = *(const float4*)(src + 12);
    *(float4*)&tile[krow][cseg]      = a0;
    *(float4*)&tile[krow][cseg + 4]  = a1;
    *(float4*)&tile[krow][cseg + 8]  = a2;
    *(float4*)&tile[krow][cseg + 12] = a3;
    __syncthreads();

    const int nrow = t >> 2, kseg = (t & 3) * 16;
    float vals[16];
    #pragma unroll
    for (int i = 0; i < 16; ++i) vals[i] = tile[kseg + i][nrow];
    const size_t orow = (size_t)(n0 + nrow) * EDIM + k0 + kseg;
    #pragma unroll
    for (int i = 0; i < 16; i += 4)
        *(float4*)(WTf + orow + i) = make_float4(vals[i], vals[i+1], vals[i+2], vals[i+3]);
}

// ============================================================
// K0c: per-feature i8 quantization of W: Wi8[24576][768], sw[24576]
// ============================================================
__global__ __launch_bounds__(256)
void quantW_i8(const float* __restrict__ WTf, unsigned char* __restrict__ Wi8,
               float* __restrict__ sw)
{
    const int w = threadIdx.x >> 6, lane = threadIdx.x & 63;
    const int row = blockIdx.x * 4 + w;
    const float* src = WTf + (size_t)row * EDIM + lane * 12;
    float d[12];
    #pragma unroll
    for (int t = 0; t < 3; ++t) {
        float4 v = *(const float4*)(src + t * 4);
        d[t*4+0] = v.x; d[t*4+1] = v.y; d[t*4+2] = v.z; d[t*4+3] = v.w;
    }
    float m = 0.f;
    #pragma unroll
    for (int j = 0; j < 12; ++j) m = fmaxf(m, fabsf(d[j]));
    #pragma unroll
    for (int s = 1; s < 64; s <<= 1) m = fmaxf(m, __shfl_xor(m, s, 64));
    const float inv = (m > 0.f) ? 127.f / m : 0.f;
    if (lane == 0) sw[row] = m / 127.f;
    uint32_t* po = (uint32_t*)(Wi8 + (size_t)row * EDIM) + lane * 3;
    #pragma unroll
    for (int t = 0; t < 3; ++t) {
        uint32_t pk = 0;
        #pragma unroll
        for (int j = 0; j < 4; ++j) {
            int q = (int)rintf(d[t*4+j] * inv);
            q = (q > 127) ? 127 : ((q < -127) ? -127 : q);
            pk |= ((uint32_t)(q & 255)) << (8 * j);
        }
        po[t] = pk;
    }
}

// ============================================================
// K1: i8 MFMA encode GEMM, 128x128 tile, 4 waves, BK=192.
// MODE 1: encode writes ONLY the 16KB contiguous cand burst per block.
// MODE 0: legacy self-zeroing layout (segments+zeros into fm).
// ============================================================
__device__ __forceinline__ void gld16(const unsigned char* g, void* l) {
    __builtin_amdgcn_global_load_lds(
        (const __attribute__((address_space(1))) void*)g,
        (__attribute__((address_space(3))) void*)l, 16, 0, 0);
}

template<int MODE>
__global__ __launch_bounds__(256)
void encode_i8_cand(const unsigned char* __restrict__ A,   // [4096][768] i8
                    const unsigned char* __restrict__ BT,  // [24576][768] i8
                    const float* __restrict__ benc,
                    const float* __restrict__ sxr,         // [4096]
                    const float* __restrict__ sw,          // [24576]
                    float* __restrict__ fm,
                    uint32_t* __restrict__ cand)           // MODE1: [192][4096][32]
{
    __shared__ int As_i[3 * 2048];   // 24 KB staging; MODE1 epilogue aliases 16 KB
    __shared__ int Bs_i[3 * 2048];   // 24 KB
    __shared__ int rowcnt[GBM];

    const int tid = threadIdx.x;
    const int l = tid & 63, w = tid >> 6;              // 4 waves
    const int wrow = (w >> 1) * 64, wcol = (w & 1) * 64;   // 2x2 wave grid
    const int lr = l & 15, lg = l >> 4;
    const int bm = blockIdx.y * GBM, bn = blockIdx.x * GBN;
    const int cb = blockIdx.x;

    // ---- staging addresses: linear idx -> (kgroup, row); dest = idx*16B ----
    const int r0 = tid & 127, g0 = tid >> 7;
    const unsigned char* gA0 = A  + (size_t)(bm + r0) * EDIM + g0 * 16;
    const unsigned char* gA1 = A  + (size_t)(bm + r0) * EDIM + (g0 + 2) * 16;
    const unsigned char* gB0 = BT + (size_t)(bn + r0) * EDIM + g0 * 16;
    const unsigned char* gB1 = BT + (size_t)(bn + r0) * EDIM + (g0 + 2) * 16;
    int* lA0 = As_i + tid * 4;
    int* lA1 = As_i + (tid + 256) * 4;
    int* lB0 = Bs_i + tid * 4;
    int* lB1 = Bs_i + (tid + 256) * 4;

    i32x4 acc[4][4];
    #pragma unroll
    for (int i = 0; i < 4; ++i)
        #pragma unroll
        for (int j = 0; j < 4; ++j)
            acc[i][j] = (i32x4){0, 0, 0, 0};

    for (int st = 0; st < 4; ++st) {                   // 4 stage groups x BK=192
        __syncthreads();
        #pragma unroll
        for (int t = 0; t < 3; ++t) {
            const int kt = st * 3 + t;
            gld16(gA0 + kt * 64, lA0 + t * 2048);
            gld16(gA1 + kt * 64, lA1 + t * 2048);
            gld16(gB0 + kt * 64, lB0 + t * 2048);
            gld16(gB1 + kt * 64, lB1 + t * 2048);
        }
        __syncthreads();

        #pragma unroll
        for (int t = 0; t < 3; ++t) {
            i32x4 af[4], bfr[4];
            #pragma unroll
            for (int f = 0; f < 4; ++f) {
                af[f]  = *(const i32x4*)&As_i[t * 2048 + (lg * 128 + wrow + f * 16 + lr) * 4];
                bfr[f] = *(const i32x4*)&Bs_i[t * 2048 + (lg * 128 + wcol + f * 16 + lr) * 4];
            }
            #pragma unroll
            for (int fi = 0; fi < 4; ++fi)
                #pragma unroll
                for (int fj = 0; fj < 4; ++fj)
                    acc[fi][fj] = __builtin_amdgcn_mfma_i32_16x16x64_i8(
                        af[fi], bfr[fj], acc[fi][fj], 0, 0, 0);
        }
    }

    float bev[4], swv[4];
    #pragma unroll
    for (int fj = 0; fj < 4; ++fj) {
        const int c = bn + wcol + fj * 16 + lr;
        bev[fj] = benc[c];
        swv[fj] = sw[c];
    }

    if (MODE == 1) {
        // -------- epilogue: compose 128 segment lines in LDS, stream 16 KB --------
        uint32_t* lseg = (uint32_t*)As_i;   // 16 KB of staging reuse
        __syncthreads();                    // all MFMA LDS reads done
        for (int i = tid; i < 4096; i += 256) lseg[i] = 0u;
        if (tid < GBM) rowcnt[tid] = 0;
        __syncthreads();

        #pragma unroll
        for (int fi = 0; fi < 4; ++fi) {
            #pragma unroll
            for (int q = 0; q < 4; ++q) {
                const int rl = wrow + fi * 16 + lg * 4 + q;
                const float srow = sxr[bm + rl];
                #pragma unroll
                for (int fj = 0; fj < 4; ++fj) {
                    const float v = (float)acc[fi][fj][q] * (srow * swv[fj]) + bev[fj];
                    if (v > T0) {
                        const int c = bn + wcol + fj * 16 + lr;
                        int p = atomicAdd(&rowcnt[rl], 1);
                        if (p < SEGCAP) {
                            lseg[rl * SEGW + 1 + p] = f2u(v);
                            lseg[rl * SEGW + 1 + SEGCAP + p] = (uint32_t)c;
                        }
                    }
                }
            }
        }
        __syncthreads();
        if (tid < GBM) lseg[tid * SEGW] = (uint32_t)rowcnt[tid];
        __syncthreads();
        // contiguous 16 KB burst: cand[(cb*4096 + bm) .. +128 rows][32w]
        int4* dst = (int4*)(cand + ((size_t)cb * BT_TOK + bm) * SEGW);
        const int4* srcl = (const int4*)lseg;
        #pragma unroll
        for (int i = 0; i < 4; ++i) dst[tid + i * 256] = srcl[tid + i * 256];
    } else {
        // -------- MODE 0: strided 128B lines in fm prefix + strided zeros --------
        for (int i = tid; i < GBM; i += 256) rowcnt[i] = 0;
        __syncthreads();
        #pragma unroll
        for (int fi = 0; fi < 4; ++fi) {
            #pragma unroll
            for (int q = 0; q < 4; ++q) {
                const int rl = wrow + fi * 16 + lg * 4 + q;
                const float srow = sxr[bm + rl];
                uint32_t* seg = (uint32_t*)(fm + (size_t)(bm + rl) * FDIM) + (size_t)cb * SEGW;
                #pragma unroll
                for (int fj = 0; fj < 4; ++fj) {
                    const float v = (float)acc[fi][fj][q] * (srow * swv[fj]) + bev[fj];
                    if (v > T0) {
                        const int c = bn + wcol + fj * 16 + lr;
                        int p = atomicAdd(&rowcnt[rl], 1);
                        if (p < SEGCAP) {
                            seg[1 + p] = f2u(v);
                            seg[1 + SEGCAP + p] = (uint32_t)c;
                        }
                    }
                }
            }
        }
        __syncthreads();
        for (int i = tid; i < GBM; i += 256) {
            uint32_t* seg = (uint32_t*)(fm + (size_t)(bm + i) * FDIM) + (size_t)cb * SEGW;
            seg[0] = (uint32_t)rowcnt[i];
        }
        if (cb >= ZCB) {
            const float4 z4 = make_float4(0.f, 0.f, 0.f, 0.f);
            const int rz = tid >> 5, cz = (tid & 31) * 4;
            #pragma unroll
            for (int p = 0; p < 16; ++p)
                *(float4*)(fm + (size_t)(bm + p * 8 + rz) * FDIM + bn + cz) = z4;
        }
    }
}

// ============================================================
// bitonic sort on 512-entry LDS arrays: desc by key, tie asc idx
// ============================================================
__device__ __forceinline__ void sort512(uint32_t* ckey, uint32_t* cidx, int tid) {
    for (int ksz = 2; ksz <= 512; ksz <<= 1) {
        for (int j = ksz >> 1; j > 0; j >>= 1) {
            for (int i = tid; i < 512; i += 256) {
                const int ixj = i ^ j;
                if (ixj > i) {
                    uint32_t ka = ckey[i], kb = ckey[ixj];
                    uint32_t ia = cidx[i], ib = cidx[ixj];
                    bool after = (ka < kb) || (ka == kb && ia > ib);
                    bool descBlock = ((i & ksz) == 0);
                    if (descBlock ? after : !after) {
                        ckey[i] = kb; ckey[ixj] = ka;
                        cidx[i] = ib; cidx[ixj] = ia;
                    }
                }
            }
            __syncthreads();
        }
    }
}

// ============================================================
// K2: gather segments -> zero own fm row (MODE1: NON-TEMPORAL stores,
// bypassing the ~1.6 TB/s cacheable-write path [R13 PMC]) -> sort ->
// fp64 band refine -> exact top-k -> scatter, decode.
// ============================================================
template<int MODE>
__global__ __launch_bounds__(256)
void topk2(float* __restrict__ fm, float* __restrict__ xrec,
           const float* __restrict__ x, const float* __restrict__ WTf,
           const float* __restrict__ Wenc, const float* __restrict__ Wdec,
           const float* __restrict__ benc, const float* __restrict__ bdec,
           const int* __restrict__ kptr, const uint32_t* __restrict__ cand)
{
    const int row = blockIdx.x;
    const int tid = threadIdx.x;
    float* lrow = fm + (size_t)row * FDIM;
    const uint32_t* lrowu = (const uint32_t*)lrow;
    const float* xr = x + (size_t)row * EDIM;
    int kk = *kptr;
    if (kk < 1) kk = 1;
    if (kk > 511) kk = 511;

    __shared__ uint32_t ckey[512];
    __shared__ uint32_t cidx[512];
    __shared__ int      segc[NSEG];
    __shared__ int      scan[256];
    __shared__ double   exd[BANDCAP];
    __shared__ int      ssel[BANDCAP];
    __shared__ int      slist[BANDCAP];
    __shared__ int      redi[256];
    __shared__ float    xd[EDIM];
    __shared__ int      badf, cc;

    // ---- read per-segment counts, detect overflow ----
    if (tid == 0) badf = 0;
    __syncthreads();
    for (int s = tid; s < NSEG; s += 256) {
        const int c = (MODE == 0)
            ? (int)lrowu[(size_t)s * SEGW]
            : (int)cand[((size_t)s * BT_TOK + row) * SEGW];
        segc[s] = c;
        if (c > SEGCAP || c < 0) atomicOr(&badf, 1);
    }
    __syncthreads();

    // ---- inclusive prefix sum over segment counts ----
    scan[tid] = (tid < NSEG) ? segc[tid] : 0;
    __syncthreads();
    for (int d = 1; d < 256; d <<= 1) {
        int v = (tid >= d) ? scan[tid - d] : 0;
        __syncthreads();
        scan[tid] += v;
        __syncthreads();
    }
    const int total = scan[NSEG - 1];

    bool fb = (badf != 0) || (total < kk) || (total > 512) || (kk > BANDCAP);
    float t32 = 0.f;

    if (!fb) {
        // ---- gather segment entries into compact LDS list ----
        for (int t = tid; t < NSEG * SEGCAP; t += 256) {
            const int s = t / SEGCAP, sl = t - s * SEGCAP;
            if (sl < segc[s]) {
                const int pos = scan[s] - segc[s] + sl;
                if (MODE == 0) {
                    ckey[pos] = lrowu[(size_t)s * SEGW + 1 + sl];
                    cidx[pos] = lrowu[(size_t)s * SEGW + 1 + SEGCAP + sl];
                } else {
                    const size_t b = ((size_t)s * BT_TOK + row) * SEGW;
                    ckey[pos] = cand[b + 1 + sl];
                    cidx[pos] = cand[b + 1 + SEGCAP + sl];
                }
            }
        }
        for (int i = total + tid; i < 512; i += 256) { ckey[i] = 0u; cidx[i] = 0u; }
        __syncthreads();
        if (MODE == 0) {
            const float4 z4 = make_float4(0.f, 0.f, 0.f, 0.f);
            for (int i = tid * 4; i < SEGPRE; i += 1024) *(float4*)(lrow + i) = z4;
        } else {
            // zero the WHOLE row with non-temporal ext-vector stores (96 KB)
            const f32x4 z4 = (f32x4){0.f, 0.f, 0.f, 0.f};
            for (int i = tid * 4; i < FDIM; i += 1024)
                __builtin_nontemporal_store(z4, (f32x4*)(lrow + i));
            // drain this wave's stores before any same-address scatter later
            asm volatile("s_waitcnt vmcnt(0)" ::: "memory");
        }
        sort512(ckey, cidx, tid);   // barriers inside cover cross-wave ordering
        t32 = u2f(ckey[kk - 1]);
        if (!(t32 - DELTA2 > T0)) fb = true;
    }

    int nb = 0;
    if (!fb) {
        const float blo = t32 - DELTA2;
        int lm = 0;
        for (int j = tid; j < total; j += 256) lm += (u2f(ckey[j]) >= blo) ? 1 : 0;
        redi[tid] = lm;
        __syncthreads();
        for (int s = 128; s > 0; s >>= 1) { if (tid < s) redi[tid] += redi[tid + s]; __syncthreads(); }
        nb = redi[0];
        if (nb > BANDCAP) fb = true;
        __syncthreads();
    }

    const int e0 = tid, e1 = tid + 256, e2 = tid + 512;

    if (fb) {
        // ---------- FALLBACK (rare): coalesced dense fp32 recompute ----------
        for (int e = tid; e < EDIM; e += 256) xd[e] = xr[e] - bdec[e];
        __syncthreads();
        for (int f0 = 0; f0 < FDIM; f0 += 256) {
            const int f = f0 + tid;
            float a0 = 0.f, a1 = 0.f, a2 = 0.f, a3 = 0.f;
            const float* wp = Wenc + f;
            #pragma unroll 4
            for (int e = 0; e < EDIM; e += 4) {
                a0 = fmaf(xd[e + 0], wp[(size_t)(e + 0) * FDIM], a0);
                a1 = fmaf(xd[e + 1], wp[(size_t)(e + 1) * FDIM], a1);
                a2 = fmaf(xd[e + 2], wp[(size_t)(e + 2) * FDIM], a2);
                a3 = fmaf(xd[e + 3], wp[(size_t)(e + 3) * FDIM], a3);
            }
            lrow[f] = (a0 + a1) + (a2 + a3) + benc[f];
        }
        __syncthreads();

        uint32_t ulo = 0u, uhi = 0xFFFFFFFFu, ut = f2u(T0);
        int state = 0; uint32_t kthu = 0u; int cfound = 0;
        for (int it = 0; it < 72; ++it) {
            if (uhi - ulo <= 1u) { state = 2; kthu = uhi; break; }
            if (ut <= ulo) ut = ulo + 1u;
            if (ut >= uhi) ut = uhi - 1u;
            const float t = u2f(ut);
            __syncthreads();
            if (tid == 0) cc = 0;
            __syncthreads();
            for (int i = tid * 4; i < FDIM; i += 1024) {
                float4 v = *(const float4*)(lrow + i);
                float vv[4] = {v.x, v.y, v.z, v.w};
                #pragma unroll
                for (int j = 0; j < 4; ++j) {
                    if (vv[j] > t) {
                        int p = atomicAdd(&cc, 1);
                        if (p < 512) { ckey[p] = f2u(vv[j]); cidx[p] = (uint32_t)(i + j); }
                    }
                }
            }
            __syncthreads();
            const int c = cc;
            if (c >= kk && c <= 512) { state = 1; cfound = c; break; }
            if (c < kk) uhi = ut; else ulo = ut;
            ut = ulo + ((uhi - ulo) >> 1);
        }
        if (state == 0) { state = 2; kthu = uhi; }

        if (state == 1) {
            for (int i = cfound + tid; i < 512; i += 256) { ckey[i] = 0u; cidx[i] = 0u; }
            __syncthreads();
            sort512(ckey, cidx, tid);
            const float kthf = u2f(ckey[kk - 1]);
            int lm = 0;
            for (int j = tid; j < cfound; j += 256) lm += (u2f(ckey[j]) >= kthf) ? 1 : 0;
            redi[tid] = lm;
            __syncthreads();
            for (int s = 128; s > 0; s >>= 1) { if (tid < s) redi[tid] += redi[tid + s]; __syncthreads(); }
            const int m = redi[0];

            const float4 z4 = make_float4(0.f, 0.f, 0.f, 0.f);
            for (int i = tid * 4; i < FDIM; i += 1024) *(float4*)(lrow + i) = z4;
            __syncthreads();
            for (int j = tid; j < m; j += 256) lrow[cidx[j]] = u2f(ckey[j]);

            float a0 = 0.f, a1 = 0.f, a2 = 0.f;
            for (int j = 0; j < m; ++j) {
                const float v = u2f(ckey[j]);
                const float* wr = Wdec + (size_t)cidx[j] * EDIM;
                a0 = fmaf(v, wr[e0], a0);
                a1 = fmaf(v, wr[e1], a1);
                a2 = fmaf(v, wr[e2], a2);
            }
            xrec[(size_t)row * EDIM + e0] = a0 + bdec[e0];
            xrec[(size_t)row * EDIM + e1] = a1 + bdec[e1];
            xrec[(size_t)row * EDIM + e2] = a2 + bdec[e2];
        } else {
            const float kthf = u2f(kthu);
            float a0 = 0.f, a1 = 0.f, a2 = 0.f;
            for (int basei = 0; basei < FDIM; basei += 512) {
                __syncthreads();
                if (tid == 0) cc = 0;
                __syncthreads();
                const int i = basei + tid * 2;
                float2 v = *(const float2*)(lrow + i);
                float2 o;
                o.x = (v.x >= kthf) ? v.x : 0.f;
                o.y = (v.y >= kthf) ? v.y : 0.f;
                *(float2*)(lrow + i) = o;
                if (v.x >= kthf) { int p = atomicAdd(&cc, 1); ckey[p] = __float_as_uint(v.x); cidx[p] = (uint32_t)i; }
                if (v.y >= kthf) { int p = atomicAdd(&cc, 1); ckey[p] = __float_as_uint(v.y); cidx[p] = (uint32_t)(i + 1); }
                __syncthreads();
                const int c = cc;
                for (int j = 0; j < c; ++j) {
                    const float v2 = __uint_as_float(ckey[j]);
                    const float* wr = Wdec + (size_t)cidx[j] * EDIM;
                    a0 = fmaf(v2, wr[e0], a0);
                    a1 = fmaf(v2, wr[e1], a1);
                    a2 = fmaf(v2, wr[e2], a2);
                }
            }
            xrec[(size_t)row * EDIM + e0] = a0 + bdec[e0];
            xrec[(size_t)row * EDIM + e1] = a1 + bdec[e1];
            xrec[(size_t)row * EDIM + e2] = a2 + bdec[e2];
        }
        return;
    }

    // ---------- MAIN PATH ----------
    const int wv = tid >> 6, ln = tid & 63;
    for (int j = wv; j < nb; j += 4) {
        const float* wt = WTf + (size_t)cidx[j] * EDIM;
        double a0d = 0.0, a1d = 0.0, a2d = 0.0;
        {
            const int ea = ln, eb = ln + 256, ec = ln + 512;
            #pragma unroll
            for (int i = 0; i < 4; ++i) {
                a0d += ((double)xr[ea + i * 64] - (double)bdec[ea + i * 64]) * (double)wt[ea + i * 64];
                a1d += ((double)xr[eb + i * 64] - (double)bdec[eb + i * 64]) * (double)wt[eb + i * 64];
                a2d += ((double)xr[ec + i * 64] - (double)bdec[ec + i * 64]) * (double)wt[ec + i * 64];
            }
        }
        double a = a0d + a1d + a2d;
        #pragma unroll
        for (int s = 32; s > 0; s >>= 1) a += __shfl_down(a, s, 64);
        if (ln == 0) exd[j] = a + (double)benc[cidx[j]];
    }
    __syncthreads();

    // exact rank selection: top kk by (value desc, idx asc, pos asc)
    for (int j = tid; j < nb; j += 256) {
        const double vj = exd[j];
        const uint32_t ij = cidx[j];
        int rank = 0;
        for (int i = 0; i < nb; ++i) {
            const double vi = exd[i];
            rank += (vi > vj || (vi == vj && (cidx[i] < ij || (cidx[i] == ij && i < j)))) ? 1 : 0;
        }
        ssel[j] = (rank < kk) ? 1 : 0;
    }
    __syncthreads();

    // selected list ordered by feature idx (deterministic decode order)
    for (int j = tid; j < nb; j += 256) {
        if (ssel[j]) {
            const uint32_t ij = cidx[j];
            int pos = 0;
            for (int i = 0; i < nb; ++i)
                pos += (ssel[i] && (cidx[i] < ij || (cidx[i] == ij && i < j))) ? 1 : 0;
            slist[pos] = j;
        }
    }
    __syncthreads();

    // scatter EXACT values into the row we zeroed above (nt stores drained
    // pre-sort via vmcnt(0); sort barriers ordered all waves since)
    for (int j = tid; j < kk; j += 256) {
        const int q = slist[j];
        lrow[cidx[q]] = (float)exd[q];
    }

    // decode with exact values
    float a0 = 0.f, a1 = 0.f, a2 = 0.f;
    for (int j = 0; j < kk; ++j) {
        const int q = slist[j];
        const float v = (float)exd[q];
        const float* wr = Wdec + (size_t)cidx[q] * EDIM;
        a0 = fmaf(v, wr[e0], a0);
        a1 = fmaf(v, wr[e1], a1);
        a2 = fmaf(v, wr[e2], a2);
    }
    xrec[(size_t)row * EDIM + e0] = a0 + bdec[e0];
    xrec[(size_t)row * EDIM + e1] = a1 + bdec[e1];
    xrec[(size_t)row * EDIM + e2] = a2 + bdec[e2];
}

// ============================================================
// FALLBACK PATH (ws too small): round-1 fp32 kernels, verbatim
// ============================================================
#define BM 128
#define BN 128
#define BKK 8
#define CAP 512

__global__ __launch_bounds__(256)
void encode_gemm(const float* __restrict__ x, const float* __restrict__ Wenc,
                 const float* __restrict__ benc, const float* __restrict__ bdec,
                 float* __restrict__ lat)
{
    __shared__ float Asf[BKK][BM];
    __shared__ float Bsf[BKK][BN];

    const int tid = threadIdx.x;
    const int tx = tid & 15, ty = tid >> 4;
    const int bm = blockIdx.y * BM;
    const int bn = blockIdx.x * BN;

    const int arow = tid >> 1, ac4 = (tid & 1) * 4;
    const int bkr  = tid >> 5, bc4 = (tid & 31) * 4;

    float acc[8][8] = {};
    float af[8], bf[8];

    for (int k0 = 0; k0 < EDIM; k0 += BKK) {
        float4 av = *(const float4*)(x + (size_t)(bm + arow) * EDIM + k0 + ac4);
        float4 bd = *(const float4*)(bdec + k0 + ac4);
        av.x -= bd.x; av.y -= bd.y; av.z -= bd.z; av.w -= bd.w;
        float4 bv = *(const float4*)(Wenc + (size_t)(k0 + bkr) * FDIM + bn + bc4);
        __syncthreads();
        Asf[ac4 + 0][arow] = av.x; Asf[ac4 + 1][arow] = av.y;
        Asf[ac4 + 2][arow] = av.z; Asf[ac4 + 3][arow] = av.w;
        *(float4*)&Bsf[bkr][bc4] = bv;
        __syncthreads();
        #pragma unroll
        for (int kkk = 0; kkk < BKK; ++kkk) {
            *(float4*)&af[0] = *(const float4*)&Asf[kkk][ty * 8];
            *(float4*)&af[4] = *(const float4*)&Asf[kkk][ty * 8 + 4];
            *(float4*)&bf[0] = *(const float4*)&Bsf[kkk][tx * 8];
            *(float4*)&bf[4] = *(const float4*)&Bsf[kkk][tx * 8 + 4];
            #pragma unroll
            for (int i = 0; i < 8; ++i)
                #pragma unroll
                for (int j = 0; j < 8; ++j)
                    acc[i][j] = fmaf(af[i], bf[j], acc[i][j]);
        }
    }

    float4 be0 = *(const float4*)(benc + bn + tx * 8);
    float4 be1 = *(const float4*)(benc + bn + tx * 8 + 4);
    #pragma unroll
    for (int i = 0; i < 8; ++i) {
        size_t ro = (size_t)(bm + ty * 8 + i) * FDIM + bn + tx * 8;
        float4 o0 = make_float4(acc[i][0] + be0.x, acc[i][1] + be0.y,
                                acc[i][2] + be0.z, acc[i][3] + be0.w);
        float4 o1 = make_float4(acc[i][4] + be1.x, acc[i][5] + be1.y,
                                acc[i][6] + be1.z, acc[i][7] + be1.w);
        *(float4*)(lat + ro)     = o0;
        *(float4*)(lat + ro + 4) = o1;
    }
}

__global__ __launch_bounds__(256)
void topk_mask_decode(float* __restrict__ lat, const float* __restrict__ Wdec,
                      const float* __restrict__ bdec, const int* __restrict__ kptr,
                      float* __restrict__ xrec)
{
    const int row = blockIdx.x;
    const int tid = threadIdx.x;
    float* lrow = lat + (size_t)row * FDIM;
    int kk = *kptr;
    if (kk < 1) kk = 1;
    if (kk > CAP) kk = CAP;

    __shared__ uint32_t ckey[CAP];
    __shared__ uint32_t cidx[CAP];
    __shared__ float redf[256];
    __shared__ int   redi[256];
    __shared__ int   cc;

    float ss = 0.f;
    for (int i = tid * 4; i < FDIM; i += 1024) {
        float4 v = *(const float4*)(lrow + i);
        ss = fmaf(v.x, v.x, fmaf(v.y, v.y, fmaf(v.z, v.z, fmaf(v.w, v.w, ss))));
    }
    redf[tid] = ss;
    __syncthreads();
    for (int s = 128; s > 0; s >>= 1) { if (tid < s) redf[tid] += redf[tid + s]; __syncthreads(); }
    const float sigma = sqrtf(redf[0] / (float)FDIM);

    uint32_t ulo = 0u, uhi = 0xFFFFFFFFu;
    uint32_t ut = f2u(2.7f * sigma);
    int state = 0; uint32_t kthu = 0u; int cfound = 0;

    for (int it = 0; it < 72; ++it) {
        if (uhi - ulo <= 1u) { state = 2; kthu = uhi; break; }
        if (ut <= ulo) ut = ulo + 1u;
        if (ut >= uhi) ut = uhi - 1u;
        const float t = u2f(ut);
        __syncthreads();
        if (tid == 0) cc = 0;
        __syncthreads();
        for (int i = tid * 4; i < FDIM; i += 1024) {
            float4 v = *(const float4*)(lrow + i);
            float vv[4] = {v.x, v.y, v.z, v.w};
            #pragma unroll
            for (int j = 0; j < 4; ++j) {
                if (vv[j] > t) {
                    int p = atomicAdd(&cc, 1);
                    if (p < CAP) { ckey[p] = f2u(vv[j]); cidx[p] = (uint32_t)(i + j); }
                }
            }
        }
        __syncthreads();
        const int c = cc;
        if (c >= kk && c <= CAP) { state = 1; cfound = c; break; }
        if (c < kk) uhi = ut; else ulo = ut;
        ut = ulo + ((uhi - ulo) >> 1);
    }
    if (state == 0) { state = 2; kthu = uhi; }

    const int e0 = tid, e1 = tid + 256, e2 = tid + 512;

    if (state == 1) {
        for (int i = cfound + tid; i < CAP; i += 256) { ckey[i] = 0u; cidx[i] = 0u; }
        __syncthreads();
        for (int ksz = 2; ksz <= CAP; ksz <<= 1) {
            for (int j = ksz >> 1; j > 0; j >>= 1) {
                for (int i = tid; i < CAP; i += 256) {
                    const int ixj = i ^ j;
                    if (ixj > i) {
                        uint32_t ka = ckey[i], kb = ckey[ixj];
                        uint32_t ia = cidx[i], ib = cidx[ixj];
                        bool after = (ka < kb) || (ka == kb && ia > ib);
                        bool descBlock = ((i & ksz) == 0);
                        if (descBlock ? after : !after) {
                            ckey[i] = kb; ckey[ixj] = ka;
                            cidx[i] = ib; cidx[ixj] = ia;
                        }
                    }
                }
                __syncthreads();
            }
        }
        const float kthf = u2f(ckey[kk - 1]);

        int lm = 0;
        for (int j2 = tid; j2 < cfound; j2 += 256) lm += (u2f(ckey[j2]) >= kthf) ? 1 : 0;
        redi[tid] = lm;
        __syncthreads();
        for (int s = 128; s > 0; s >>= 1) { if (tid < s) redi[tid] += redi[tid + s]; __syncthreads(); }
        const int m = redi[0];

        const float4 z4 = make_float4(0.f, 0.f, 0.f, 0.f);
        for (int i = tid * 4; i < FDIM; i += 1024) *(float4*)(lrow + i) = z4;
        __syncthreads();
        for (int j2 = tid; j2 < m; j2 += 256) lrow[cidx[j2]] = u2f(ckey[j2]);

        float a0 = 0.f, a1 = 0.f, a2 = 0.f;
        for (int j2 = 0; j2 < m; ++j2) {
            const float v = u2f(ckey[j2]);
            const float* wr = Wdec + (size_t)cidx[j2] * EDIM;
            a0 = fmaf(v, wr[e0], a0);
            a1 = fmaf(v, wr[e1], a1);
            a2 = fmaf(v, wr[e2], a2);
        }
        xrec[(size_t)row * EDIM + e0] = a0 + bdec[e0];
        xrec[(size_t)row * EDIM + e1] = a1 + bdec[e1];
        xrec[(size_t)row * EDIM + e2] = a2 + bdec[e2];
    } else {
        const float kthf = u2f(kthu);
        float a0 = 0.f, a1 = 0.f, a2 = 0.f;
        for (int base = 0; base < FDIM; base += 512) {
            __syncthreads();
            if (tid == 0) cc = 0;
            __syncthreads();
            const int i = base + tid * 2;
            float2 v = *(const float2*)(lrow + i);
            float2 o;
            o.x = (v.x >= kthf) ? v.x : 0.f;
            o.y = (v.y >= kthf) ? v.y : 0.f;
            *(float2*)(lrow + i) = o;
            if (v.x >= kthf) { int p = atomicAdd(&cc, 1); ckey[p] = __float_as_uint(v.x); cidx[p] = (uint32_t)i; }
            if (v.y >= kthf) { int p = atomicAdd(&cc, 1); ckey[p] = __float_as_uint(v.y); cidx[p] = (uint32_t)(i + 1); }
            __syncthreads();
            const int c = cc;
            for (int j2 = 0; j2 < c; ++j2) {
                const float v2 = __uint_as_float(ckey[j2]);
                const float* wr = Wdec + (size_t)cidx[j2] * EDIM;
                a0 = fmaf(v2, wr[e0], a0);
                a1 = fmaf(v2, wr[e1], a1);
                a2 = fmaf(v2, wr[e2], a2);
            }
        }
        xrec[(size_t)row * EDIM + e0] = a0 + bdec[e0];
        xrec[(size_t)row * EDIM + e1] = a1 + bdec[e1];
        xrec[(size_t)row * EDIM + e2] = a2 + bdec[e2];
    }
}

// ============================================================
extern "C" void kernel_launch(void* const* d_in, const int* in_sizes, int n_in,
                              void* d_out, int out_size, void* d_ws, size_t ws_size,
                              hipStream_t stream) {
    const float* x    = (const float*)d_in[0];
    const float* Wenc = (const float*)d_in[1];
    const float* Wdec = (const float*)d_in[2];
    const float* benc = (const float*)d_in[3];
    const float* bdec = (const float*)d_in[4];
    const int*   kptr = (const int*)d_in[5];

    float* xrec = (float*)d_out;                          // (4096, 768)
    float* fm   = (float*)d_out + (size_t)BT_TOK * EDIM;  // (4096, 24576)

    const size_t szAi = (size_t)BT_TOK * EDIM;            //  3,145,728 (i8)
    const size_t szWi = (size_t)FDIM * EDIM;              // 18,874,368 (i8)
    const size_t szWT = (size_t)FDIM * EDIM * 4;          // 75,497,472 (f32)
    const size_t szSx = (size_t)BT_TOK * 4;
    const size_t szSw = (size_t)FDIM * 4;
    const size_t base = szAi + szWi + szWT + szSx + szSw;
    const size_t szCd = (size_t)NSEG * BT_TOK * SEGW * 4; // 100,663,296

    if (ws_size >= base) {
        unsigned char* Ai8 = (unsigned char*)d_ws;
        unsigned char* Wi8 = (unsigned char*)d_ws + szAi;
        float*         WTf = (float*)((char*)d_ws + szAi + szWi);
        float*         sxr = (float*)((char*)d_ws + szAi + szWi + szWT);
        float*         sw  = (float*)((char*)d_ws + szAi + szWi + szWT + szSx);
        uint32_t*      cnd = (uint32_t*)((char*)d_ws + base);

        build_A_i8<<<BT_TOK / 4, 256, 0, stream>>>(x, bdec, Ai8, sxr);
        build_WT<<<dim3(FDIM / TT, EDIM / TT), 256, 0, stream>>>(Wenc, WTf);
        quantW_i8<<<FDIM / 4, 256, 0, stream>>>(WTf, Wi8, sw);
        if (ws_size >= base + szCd) {
            encode_i8_cand<1><<<dim3(FDIM / GBN, BT_TOK / GBM), 256, 0, stream>>>(
                Ai8, Wi8, benc, sxr, sw, fm, cnd);
            topk2<1><<<BT_TOK, 256, 0, stream>>>(fm, xrec, x, WTf, Wenc, Wdec,
                                                 benc, bdec, kptr, cnd);
        } else {
            encode_i8_cand<0><<<dim3(FDIM / GBN, BT_TOK / GBM), 256, 0, stream>>>(
                Ai8, Wi8, benc, sxr, sw, fm, nullptr);
            topk2<0><<<BT_TOK, 256, 0, stream>>>(fm, xrec, x, WTf, Wenc, Wdec,
                                                 benc, bdec, kptr, nullptr);
        }
    } else {
        dim3 g1(FDIM / BN, BT_TOK / BM);
        encode_gemm<<<g1, 256, 0, stream>>>(x, Wenc, benc, bdec, fm);
        topk_mask_decode<<<BT_TOK, 256, 0, stream>>>(fm, Wdec, bdec, kptr, xrec);
    }
}

// Round 16
// 468.039 us; speedup vs baseline: 1.0949x; 1.0278x over previous
//
#include <hip/hip_runtime.h>
#include <stdint.h>

#define BT_TOK 4096
#define EDIM 768
#define FDIM 24576

// ---------- monotone float<->uint transform (order-preserving) ----------
__device__ __forceinline__ uint32_t f2u(float f) {
    uint32_t b = __float_as_uint(f);
    return (b & 0x80000000u) ? ~b : (b | 0x80000000u);
}
__device__ __forceinline__ float u2f(uint32_t u) {
    uint32_t b = (u & 0x80000000u) ? (u & 0x7FFFFFFFu) : ~u;
    return __uint_as_float(b);
}

#define GBM 128             // encode tile rows (4 waves, 2x2 wave grid)
#define GBN 128             // encode tile cols
#define NSEG (FDIM / GBN)   // 192 column-block segments per row
#define SEGW 32             // words per segment = 128 B
#define SEGCAP 15           // [0]=count, [1..15]=keys, [16..30]=idx, [31]=pad
#define SEGPRE (NSEG * SEGW) // 6144 words (MODE 0 layout)
#define ZCB (SEGPRE / GBN)   // 48 (MODE 0)
#define BANDCAP 160
#define T0 0.6f
#define DELTA2 0.035f        // i8-quant noise band: 2 x 6 sigma

typedef int   i32x4 __attribute__((ext_vector_type(4)));
typedef float f32x4 __attribute__((ext_vector_type(4)));

// ============================================================
// K0a: per-row i8 quantization of (x - b_dec): Ai8[4096][768], sxr[4096]
// ============================================================
__global__ __launch_bounds__(256)
void build_A_i8(const float* __restrict__ x, const float* __restrict__ bdec,
                unsigned char* __restrict__ Ai8, float* __restrict__ sxr)
{
    const int w = threadIdx.x >> 6, lane = threadIdx.x & 63;
    const int row = blockIdx.x * 4 + w;
    const float* src = x + (size_t)row * EDIM + lane * 12;
    const float* bd  = bdec + lane * 12;
    float d[12];
    #pragma unroll
    for (int t = 0; t < 3; ++t) {
        float4 v = *(const float4*)(src + t * 4);
        float4 b = *(const float4*)(bd + t * 4);
        d[t*4+0] = v.x - b.x; d[t*4+1] = v.y - b.y;
        d[t*4+2] = v.z - b.z; d[t*4+3] = v.w - b.w;
    }
    float m = 0.f;
    #pragma unroll
    for (int j = 0; j < 12; ++j) m = fmaxf(m, fabsf(d[j]));
    #pragma unroll
    for (int s = 1; s < 64; s <<= 1) m = fmaxf(m, __shfl_xor(m, s, 64));
    const float inv = (m > 0.f) ? 127.f / m : 0.f;
    if (lane == 0) sxr[row] = m / 127.f;
    uint32_t* po = (uint32_t*)(Ai8 + (size_t)row * EDIM) + lane * 3;
    #pragma unroll
    for (int t = 0; t < 3; ++t) {
        uint32_t pk = 0;
        #pragma unroll
        for (int j = 0; j < 4; ++j) {
            int q = (int)rintf(d[t*4+j] * inv);
            q = (q > 127) ? 127 : ((q < -127) ? -127 : q);
            pk |= ((uint32_t)(q & 255)) << (8 * j);
        }
        po[t] = pk;
    }
}

// ============================================================
// K0b: W_enc [768][24576] -> WTf fp32 [24576][768]  (transpose only)
// ============================================================
#define TT 64
__global__ __launch_bounds__(256)
void build_WT(const float* __restrict__ Wenc, float* __restrict__ WTf)
{
    __shared__ float tile[TT][TT + 4];
    const int n0 = blockIdx.x * TT, k0 = blockIdx.y * TT;
    const int t = threadIdx.x;

    const int krow = t >> 2, cseg = (t & 3) * 16;
    const float* src = Wenc + (size_t)(k0 + krow) * FDIM + n0 + cseg;
    float4 a0 = *(const float4*)(src);
    float4 a1 = *(const float4*)(src + 4);
    float4 a2 = *(const float4*)(src + 8);
    float4 a3 = *(const float4*)(src + 12);
    *(float4*)&tile[krow][cseg]      = a0;
    *(float4*)&tile[krow][cseg + 4]  = a1;
    *(float4*)&tile[krow][cseg + 8]  = a2;
    *(float4*)&tile[krow][cseg + 12] = a3;
    __syncthreads();

    const int nrow = t >> 2, kseg = (t & 3) * 16;
    float vals[16];
    #pragma unroll
    for (int i = 0; i < 16; ++i) vals[i] = tile[kseg + i][nrow];
    const size_t orow = (size_t)(n0 + nrow) * EDIM + k0 + kseg;
    #pragma unroll
    for (int i = 0; i < 16; i += 4)
        *(float4*)(WTf + orow + i) = make_float4(vals[i], vals[i+1], vals[i+2], vals[i+3]);
}

// ============================================================
// K0c: per-feature i8 quantization of W: Wi8[24576][768], sw[24576]
// ============================================================
__global__ __launch_bounds__(256)
void quantW_i8(const float* __restrict__ WTf, unsigned char* __restrict__ Wi8,
               float* __restrict__ sw)
{
    const int w = threadIdx.x >> 6, lane = threadIdx.x & 63;
    const int row = blockIdx.x * 4 + w;
    const float* src = WTf + (size_t)row * EDIM + lane * 12;
    float d[12];
    #pragma unroll
    for (int t = 0; t < 3; ++t) {
        float4 v = *(const float4*)(src + t * 4);
        d[t*4+0] = v.x; d[t*4+1] = v.y; d[t*4+2] = v.z; d[t*4+3] = v.w;
    }
    float m = 0.f;
    #pragma unroll
    for (int j = 0; j < 12; ++j) m = fmaxf(m, fabsf(d[j]));
    #pragma unroll
    for (int s = 1; s < 64; s <<= 1) m = fmaxf(m, __shfl_xor(m, s, 64));
    const float inv = (m > 0.f) ? 127.f / m : 0.f;
    if (lane == 0) sw[row] = m / 127.f;
    uint32_t* po = (uint32_t*)(Wi8 + (size_t)row * EDIM) + lane * 3;
    #pragma unroll
    for (int t = 0; t < 3; ++t) {
        uint32_t pk = 0;
        #pragma unroll
        for (int j = 0; j < 4; ++j) {
            int q = (int)rintf(d[t*4+j] * inv);
            q = (q > 127) ? 127 : ((q < -127) ? -127 : q);
            pk |= ((uint32_t)(q & 255)) << (8 * j);
        }
        po[t] = pk;
    }
}

// ============================================================
// K1: i8 MFMA encode GEMM, 128x128 tile, 4 waves, BK=192.
// MODE 1: writes the 16KB contiguous cand burst + NT-zeros its own
// contiguous 64KB fm slab at kernel END (no trailing barrier — stores
// retire under other blocks' compute; dispatch fence publishes them).
// MODE 0: legacy self-zeroing layout (segments+zeros into fm).
// ============================================================
__device__ __forceinline__ void gld16(const unsigned char* g, void* l) {
    __builtin_amdgcn_global_load_lds(
        (const __attribute__((address_space(1))) void*)g,
        (__attribute__((address_space(3))) void*)l, 16, 0, 0);
}

template<int MODE>
__global__ __launch_bounds__(256)
void encode_i8_cand(const unsigned char* __restrict__ A,   // [4096][768] i8
                    const unsigned char* __restrict__ BT,  // [24576][768] i8
                    const float* __restrict__ benc,
                    const float* __restrict__ sxr,         // [4096]
                    const float* __restrict__ sw,          // [24576]
                    float* __restrict__ fm,
                    uint32_t* __restrict__ cand)           // MODE1: [192][4096][32]
{
    __shared__ int As_i[3 * 2048];   // 24 KB staging; MODE1 epilogue aliases 16 KB
    __shared__ int Bs_i[3 * 2048];   // 24 KB
    __shared__ int rowcnt[GBM];

    const int tid = threadIdx.x;
    const int l = tid & 63, w = tid >> 6;              // 4 waves
    const int wrow = (w >> 1) * 64, wcol = (w & 1) * 64;   // 2x2 wave grid
    const int lr = l & 15, lg = l >> 4;
    const int bm = blockIdx.y * GBM, bn = blockIdx.x * GBN;
    const int cb = blockIdx.x;

    // ---- staging addresses: linear idx -> (kgroup, row); dest = idx*16B ----
    const int r0 = tid & 127, g0 = tid >> 7;
    const unsigned char* gA0 = A  + (size_t)(bm + r0) * EDIM + g0 * 16;
    const unsigned char* gA1 = A  + (size_t)(bm + r0) * EDIM + (g0 + 2) * 16;
    const unsigned char* gB0 = BT + (size_t)(bn + r0) * EDIM + g0 * 16;
    const unsigned char* gB1 = BT + (size_t)(bn + r0) * EDIM + (g0 + 2) * 16;
    int* lA0 = As_i + tid * 4;
    int* lA1 = As_i + (tid + 256) * 4;
    int* lB0 = Bs_i + tid * 4;
    int* lB1 = Bs_i + (tid + 256) * 4;

    i32x4 acc[4][4];
    #pragma unroll
    for (int i = 0; i < 4; ++i)
        #pragma unroll
        for (int j = 0; j < 4; ++j)
            acc[i][j] = (i32x4){0, 0, 0, 0};

    for (int st = 0; st < 4; ++st) {                   // 4 stage groups x BK=192
        __syncthreads();
        #pragma unroll
        for (int t = 0; t < 3; ++t) {
            const int kt = st * 3 + t;
            gld16(gA0 + kt * 64, lA0 + t * 2048);
            gld16(gA1 + kt * 64, lA1 + t * 2048);
            gld16(gB0 + kt * 64, lB0 + t * 2048);
            gld16(gB1 + kt * 64, lB1 + t * 2048);
        }
        __syncthreads();

        #pragma unroll
        for (int t = 0; t < 3; ++t) {
            i32x4 af[4], bfr[4];
            #pragma unroll
            for (int f = 0; f < 4; ++f) {
                af[f]  = *(const i32x4*)&As_i[t * 2048 + (lg * 128 + wrow + f * 16 + lr) * 4];
                bfr[f] = *(const i32x4*)&Bs_i[t * 2048 + (lg * 128 + wcol + f * 16 + lr) * 4];
            }
            #pragma unroll
            for (int fi = 0; fi < 4; ++fi)
                #pragma unroll
                for (int fj = 0; fj < 4; ++fj)
                    acc[fi][fj] = __builtin_amdgcn_mfma_i32_16x16x64_i8(
                        af[fi], bfr[fj], acc[fi][fj], 0, 0, 0);
        }
    }

    float bev[4], swv[4];
    #pragma unroll
    for (int fj = 0; fj < 4; ++fj) {
        const int c = bn + wcol + fj * 16 + lr;
        bev[fj] = benc[c];
        swv[fj] = sw[c];
    }

    if (MODE == 1) {
        // -------- epilogue: compose 128 segment lines in LDS, stream 16 KB --------
        uint32_t* lseg = (uint32_t*)As_i;   // 16 KB of staging reuse
        __syncthreads();                    // all MFMA LDS reads done
        for (int i = tid; i < 4096; i += 256) lseg[i] = 0u;
        if (tid < GBM) rowcnt[tid] = 0;
        __syncthreads();

        #pragma unroll
        for (int fi = 0; fi < 4; ++fi) {
            #pragma unroll
            for (int q = 0; q < 4; ++q) {
                const int rl = wrow + fi * 16 + lg * 4 + q;
                const float srow = sxr[bm + rl];
                #pragma unroll
                for (int fj = 0; fj < 4; ++fj) {
                    const float v = (float)acc[fi][fj][q] * (srow * swv[fj]) + bev[fj];
                    if (v > T0) {
                        const int c = bn + wcol + fj * 16 + lr;
                        int p = atomicAdd(&rowcnt[rl], 1);
                        if (p < SEGCAP) {
                            lseg[rl * SEGW + 1 + p] = f2u(v);
                            lseg[rl * SEGW + 1 + SEGCAP + p] = (uint32_t)c;
                        }
                    }
                }
            }
        }
        __syncthreads();
        if (tid < GBM) lseg[tid * SEGW] = (uint32_t)rowcnt[tid];
        __syncthreads();
        // contiguous 16 KB burst: cand[(cb*4096 + bm) .. +128 rows][32w]
        int4* dst = (int4*)(cand + ((size_t)cb * BT_TOK + bm) * SEGW);
        const int4* srcl = (const int4*)lseg;
        #pragma unroll
        for (int i = 0; i < 4; ++i) dst[tid + i * 256] = srcl[tid + i * 256];

        // -------- nt-zero own contiguous 64 KB fm slab (kernel end, no barrier):
        // grid is 192x32 = 6144 blocks x 16384 floats = full fm region.
        {
            const int lid = blockIdx.y * gridDim.x + blockIdx.x;
            f32x4* slab = (f32x4*)(fm + (size_t)lid * 16384);
            const f32x4 z4 = (f32x4){0.f, 0.f, 0.f, 0.f};
            #pragma unroll
            for (int i = 0; i < 16; ++i)
                __builtin_nontemporal_store(z4, slab + tid + i * 256);
        }
    } else {
        // -------- MODE 0: strided 128B lines in fm prefix + strided zeros --------
        for (int i = tid; i < GBM; i += 256) rowcnt[i] = 0;
        __syncthreads();
        #pragma unroll
        for (int fi = 0; fi < 4; ++fi) {
            #pragma unroll
            for (int q = 0; q < 4; ++q) {
                const int rl = wrow + fi * 16 + lg * 4 + q;
                const float srow = sxr[bm + rl];
                uint32_t* seg = (uint32_t*)(fm + (size_t)(bm + rl) * FDIM) + (size_t)cb * SEGW;
                #pragma unroll
                for (int fj = 0; fj < 4; ++fj) {
                    const float v = (float)acc[fi][fj][q] * (srow * swv[fj]) + bev[fj];
                    if (v > T0) {
                        const int c = bn + wcol + fj * 16 + lr;
                        int p = atomicAdd(&rowcnt[rl], 1);
                        if (p < SEGCAP) {
                            seg[1 + p] = f2u(v);
                            seg[1 + SEGCAP + p] = (uint32_t)c;
                        }
                    }
                }
            }
        }
        __syncthreads();
        for (int i = tid; i < GBM; i += 256) {
            uint32_t* seg = (uint32_t*)(fm + (size_t)(bm + i) * FDIM) + (size_t)cb * SEGW;
            seg[0] = (uint32_t)rowcnt[i];
        }
        if (cb >= ZCB) {
            const float4 z4 = make_float4(0.f, 0.f, 0.f, 0.f);
            const int rz = tid >> 5, cz = (tid & 31) * 4;
            #pragma unroll
            for (int p = 0; p < 16; ++p)
                *(float4*)(fm + (size_t)(bm + p * 8 + rz) * FDIM + bn + cz) = z4;
        }
    }
}

// ============================================================
// bitonic sort on 512-entry LDS arrays: desc by key, tie asc idx
// ============================================================
__device__ __forceinline__ void sort512(uint32_t* ckey, uint32_t* cidx, int tid) {
    for (int ksz = 2; ksz <= 512; ksz <<= 1) {
        for (int j = ksz >> 1; j > 0; j >>= 1) {
            for (int i = tid; i < 512; i += 256) {
                const int ixj = i ^ j;
                if (ixj > i) {
                    uint32_t ka = ckey[i], kb = ckey[ixj];
                    uint32_t ia = cidx[i], ib = cidx[ixj];
                    bool after = (ka < kb) || (ka == kb && ia > ib);
                    bool descBlock = ((i & ksz) == 0);
                    if (descBlock ? after : !after) {
                        ckey[i] = kb; ckey[ixj] = ka;
                        cidx[i] = ib; cidx[ixj] = ia;
                    }
                }
            }
            __syncthreads();
        }
    }
}

// ============================================================
// K2: gather segments -> sort -> fp64 band refine -> exact top-k ->
// scatter into PRE-ZEROED fm row (encode nt-zeroed it), decode.
// MODE 0 zeroes its own prefix (legacy). Fallback recomputes densely.
// ============================================================
template<int MODE>
__global__ __launch_bounds__(256)
void topk2(float* __restrict__ fm, float* __restrict__ xrec,
           const float* __restrict__ x, const float* __restrict__ WTf,
           const float* __restrict__ Wenc, const float* __restrict__ Wdec,
           const float* __restrict__ benc, const float* __restrict__ bdec,
           const int* __restrict__ kptr, const uint32_t* __restrict__ cand)
{
    const int row = blockIdx.x;
    const int tid = threadIdx.x;
    float* lrow = fm + (size_t)row * FDIM;
    const uint32_t* lrowu = (const uint32_t*)lrow;
    const float* xr = x + (size_t)row * EDIM;
    int kk = *kptr;
    if (kk < 1) kk = 1;
    if (kk > 511) kk = 511;

    __shared__ uint32_t ckey[512];
    __shared__ uint32_t cidx[512];
    __shared__ int      segc[NSEG];
    __shared__ int      scan[256];
    __shared__ double   exd[BANDCAP];
    __shared__ int      ssel[BANDCAP];
    __shared__ int      slist[BANDCAP];
    __shared__ int      redi[256];
    __shared__ float    xd[EDIM];
    __shared__ int      badf, cc;

    // ---- read per-segment counts, detect overflow ----
    if (tid == 0) badf = 0;
    __syncthreads();
    for (int s = tid; s < NSEG; s += 256) {
        const int c = (MODE == 0)
            ? (int)lrowu[(size_t)s * SEGW]
            : (int)cand[((size_t)s * BT_TOK + row) * SEGW];
        segc[s] = c;
        if (c > SEGCAP || c < 0) atomicOr(&badf, 1);
    }
    __syncthreads();

    // ---- inclusive prefix sum over segment counts ----
    scan[tid] = (tid < NSEG) ? segc[tid] : 0;
    __syncthreads();
    for (int d = 1; d < 256; d <<= 1) {
        int v = (tid >= d) ? scan[tid - d] : 0;
        __syncthreads();
        scan[tid] += v;
        __syncthreads();
    }
    const int total = scan[NSEG - 1];

    bool fb = (badf != 0) || (total < kk) || (total > 512) || (kk > BANDCAP);
    float t32 = 0.f;

    if (!fb) {
        // ---- gather segment entries into compact LDS list ----
        for (int t = tid; t < NSEG * SEGCAP; t += 256) {
            const int s = t / SEGCAP, sl = t - s * SEGCAP;
            if (sl < segc[s]) {
                const int pos = scan[s] - segc[s] + sl;
                if (MODE == 0) {
                    ckey[pos] = lrowu[(size_t)s * SEGW + 1 + sl];
                    cidx[pos] = lrowu[(size_t)s * SEGW + 1 + SEGCAP + sl];
                } else {
                    const size_t b = ((size_t)s * BT_TOK + row) * SEGW;
                    ckey[pos] = cand[b + 1 + sl];
                    cidx[pos] = cand[b + 1 + SEGCAP + sl];
                }
            }
        }
        for (int i = total + tid; i < 512; i += 256) { ckey[i] = 0u; cidx[i] = 0u; }
        __syncthreads();
        if (MODE == 0) {
            const float4 z4 = make_float4(0.f, 0.f, 0.f, 0.f);
            for (int i = tid * 4; i < SEGPRE; i += 1024) *(float4*)(lrow + i) = z4;
        }
        // MODE 1: fm row already nt-zeroed by encode (dispatch fence publishes)
        sort512(ckey, cidx, tid);
        t32 = u2f(ckey[kk - 1]);
        if (!(t32 - DELTA2 > T0)) fb = true;
    }

    int nb = 0;
    if (!fb) {
        const float blo = t32 - DELTA2;
        int lm = 0;
        for (int j = tid; j < total; j += 256) lm += (u2f(ckey[j]) >= blo) ? 1 : 0;
        redi[tid] = lm;
        __syncthreads();
        for (int s = 128; s > 0; s >>= 1) { if (tid < s) redi[tid] += redi[tid + s]; __syncthreads(); }
        nb = redi[0];
        if (nb > BANDCAP) fb = true;
        __syncthreads();
    }

    const int e0 = tid, e1 = tid + 256, e2 = tid + 512;

    if (fb) {
        // ---------- FALLBACK (rare): coalesced dense fp32 recompute ----------
        for (int e = tid; e < EDIM; e += 256) xd[e] = xr[e] - bdec[e];
        __syncthreads();
        for (int f0 = 0; f0 < FDIM; f0 += 256) {
            const int f = f0 + tid;
            float a0 = 0.f, a1 = 0.f, a2 = 0.f, a3 = 0.f;
            const float* wp = Wenc + f;
            #pragma unroll 4
            for (int e = 0; e < EDIM; e += 4) {
                a0 = fmaf(xd[e + 0], wp[(size_t)(e + 0) * FDIM], a0);
                a1 = fmaf(xd[e + 1], wp[(size_t)(e + 1) * FDIM], a1);
                a2 = fmaf(xd[e + 2], wp[(size_t)(e + 2) * FDIM], a2);
                a3 = fmaf(xd[e + 3], wp[(size_t)(e + 3) * FDIM], a3);
            }
            lrow[f] = (a0 + a1) + (a2 + a3) + benc[f];
        }
        __syncthreads();

        uint32_t ulo = 0u, uhi = 0xFFFFFFFFu, ut = f2u(T0);
        int state = 0; uint32_t kthu = 0u; int cfound = 0;
        for (int it = 0; it < 72; ++it) {
            if (uhi - ulo <= 1u) { state = 2; kthu = uhi; break; }
            if (ut <= ulo) ut = ulo + 1u;
            if (ut >= uhi) ut = uhi - 1u;
            const float t = u2f(ut);
            __syncthreads();
            if (tid == 0) cc = 0;
            __syncthreads();
            for (int i = tid * 4; i < FDIM; i += 1024) {
                float4 v = *(const float4*)(lrow + i);
                float vv[4] = {v.x, v.y, v.z, v.w};
                #pragma unroll
                for (int j = 0; j < 4; ++j) {
                    if (vv[j] > t) {
                        int p = atomicAdd(&cc, 1);
                        if (p < 512) { ckey[p] = f2u(vv[j]); cidx[p] = (uint32_t)(i + j); }
                    }
                }
            }
            __syncthreads();
            const int c = cc;
            if (c >= kk && c <= 512) { state = 1; cfound = c; break; }
            if (c < kk) uhi = ut; else ulo = ut;
            ut = ulo + ((uhi - ulo) >> 1);
        }
        if (state == 0) { state = 2; kthu = uhi; }

        if (state == 1) {
            for (int i = cfound + tid; i < 512; i += 256) { ckey[i] = 0u; cidx[i] = 0u; }
            __syncthreads();
            sort512(ckey, cidx, tid);
            const float kthf = u2f(ckey[kk - 1]);
            int lm = 0;
            for (int j = tid; j < cfound; j += 256) lm += (u2f(ckey[j]) >= kthf) ? 1 : 0;
            redi[tid] = lm;
            __syncthreads();
            for (int s = 128; s > 0; s >>= 1) { if (tid < s) redi[tid] += redi[tid + s]; __syncthreads(); }
            const int m = redi[0];

            const float4 z4 = make_float4(0.f, 0.f, 0.f, 0.f);
            for (int i = tid * 4; i < FDIM; i += 1024) *(float4*)(lrow + i) = z4;
            __syncthreads();
            for (int j = tid; j < m; j += 256) lrow[cidx[j]] = u2f(ckey[j]);

            float a0 = 0.f, a1 = 0.f, a2 = 0.f;
            for (int j = 0; j < m; ++j) {
                const float v = u2f(ckey[j]);
                const float* wr = Wdec + (size_t)cidx[j] * EDIM;
                a0 = fmaf(v, wr[e0], a0);
                a1 = fmaf(v, wr[e1], a1);
                a2 = fmaf(v, wr[e2], a2);
            }
            xrec[(size_t)row * EDIM + e0] = a0 + bdec[e0];
            xrec[(size_t)row * EDIM + e1] = a1 + bdec[e1];
            xrec[(size_t)row * EDIM + e2] = a2 + bdec[e2];
        } else {
            const float kthf = u2f(kthu);
            float a0 = 0.f, a1 = 0.f, a2 = 0.f;
            for (int basei = 0; basei < FDIM; basei += 512) {
                __syncthreads();
                if (tid == 0) cc = 0;
                __syncthreads();
                const int i = basei + tid * 2;
                float2 v = *(const float2*)(lrow + i);
                float2 o;
                o.x = (v.x >= kthf) ? v.x : 0.f;
                o.y = (v.y >= kthf) ? v.y : 0.f;
                *(float2*)(lrow + i) = o;
                if (v.x >= kthf) { int p = atomicAdd(&cc, 1); ckey[p] = __float_as_uint(v.x); cidx[p] = (uint32_t)i; }
                if (v.y >= kthf) { int p = atomicAdd(&cc, 1); ckey[p] = __float_as_uint(v.y); cidx[p] = (uint32_t)(i + 1); }
                __syncthreads();
                const int c = cc;
                for (int j = 0; j < c; ++j) {
                    const float v2 = __uint_as_float(ckey[j]);
                    const float* wr = Wdec + (size_t)cidx[j] * EDIM;
                    a0 = fmaf(v2, wr[e0], a0);
                    a1 = fmaf(v2, wr[e1], a1);
                    a2 = fmaf(v2, wr[e2], a2);
                }
            }
            xrec[(size_t)row * EDIM + e0] = a0 + bdec[e0];
            xrec[(size_t)row * EDIM + e1] = a1 + bdec[e1];
            xrec[(size_t)row * EDIM + e2] = a2 + bdec[e2];
        }
        return;
    }

    // ---------- MAIN PATH ----------
    const int wv = tid >> 6, ln = tid & 63;
    for (int j = wv; j < nb; j += 4) {
        const float* wt = WTf + (size_t)cidx[j] * EDIM;
        double a0d = 0.0, a1d = 0.0, a2d = 0.0;
        {
            const int ea = ln, eb = ln + 256, ec = ln + 512;
            #pragma unroll
            for (int i = 0; i < 4; ++i) {
                a0d += ((double)xr[ea + i * 64] - (double)bdec[ea + i * 64]) * (double)wt[ea + i * 64];
                a1d += ((double)xr[eb + i * 64] - (double)bdec[eb + i * 64]) * (double)wt[eb + i * 64];
                a2d += ((double)xr[ec + i * 64] - (double)bdec[ec + i * 64]) * (double)wt[ec + i * 64];
            }
        }
        double a = a0d + a1d + a2d;
        #pragma unroll
        for (int s = 32; s > 0; s >>= 1) a += __shfl_down(a, s, 64);
        if (ln == 0) exd[j] = a + (double)benc[cidx[j]];
    }
    __syncthreads();

    // exact rank selection: top kk by (value desc, idx asc, pos asc)
    for (int j = tid; j < nb; j += 256) {
        const double vj = exd[j];
        const uint32_t ij = cidx[j];
        int rank = 0;
        for (int i = 0; i < nb; ++i) {
            const double vi = exd[i];
            rank += (vi > vj || (vi == vj && (cidx[i] < ij || (cidx[i] == ij && i < j)))) ? 1 : 0;
        }
        ssel[j] = (rank < kk) ? 1 : 0;
    }
    __syncthreads();

    // selected list ordered by feature idx (deterministic decode order)
    for (int j = tid; j < nb; j += 256) {
        if (ssel[j]) {
            const uint32_t ij = cidx[j];
            int pos = 0;
            for (int i = 0; i < nb; ++i)
                pos += (ssel[i] && (cidx[i] < ij || (cidx[i] == ij && i < j))) ? 1 : 0;
            slist[pos] = j;
        }
    }
    __syncthreads();

    // scatter EXACT values into the pre-zeroed fm row
    for (int j = tid; j < kk; j += 256) {
        const int q = slist[j];
        lrow[cidx[q]] = (float)exd[q];
    }

    // decode with exact values
    float a0 = 0.f, a1 = 0.f, a2 = 0.f;
    for (int j = 0; j < kk; ++j) {
        const int q = slist[j];
        const float v = (float)exd[q];
        const float* wr = Wdec + (size_t)cidx[q] * EDIM;
        a0 = fmaf(v, wr[e0], a0);
        a1 = fmaf(v, wr[e1], a1);
        a2 = fmaf(v, wr[e2], a2);
    }
    xrec[(size_t)row * EDIM + e0] = a0 + bdec[e0];
    xrec[(size_t)row * EDIM + e1] = a1 + bdec[e1];
    xrec[(size_t)row * EDIM + e2] = a2 + bdec[e2];
}

// ============================================================
// FALLBACK PATH (ws too small): round-1 fp32 kernels, verbatim
// ============================================================
#define BM 128
#define BN 128
#define BKK 8
#define CAP 512

__global__ __launch_bounds__(256)
void encode_gemm(const float* __restrict__ x, const float* __restrict__ Wenc,
                 const float* __restrict__ benc, const float* __restrict__ bdec,
                 float* __restrict__ lat)
{
    __shared__ float Asf[BKK][BM];
    __shared__ float Bsf[BKK][BN];

    const int tid = threadIdx.x;
    const int tx = tid & 15, ty = tid >> 4;
    const int bm = blockIdx.y * BM;
    const int bn = blockIdx.x * BN;

    const int arow = tid >> 1, ac4 = (tid & 1) * 4;
    const int bkr  = tid >> 5, bc4 = (tid & 31) * 4;

    float acc[8][8] = {};
    float af[8], bf[8];

    for (int k0 = 0; k0 < EDIM; k0 += BKK) {
        float4 av = *(const float4*)(x + (size_t)(bm + arow) * EDIM + k0 + ac4);
        float4 bd = *(const float4*)(bdec + k0 + ac4);
        av.x -= bd.x; av.y -= bd.y; av.z -= bd.z; av.w -= bd.w;
        float4 bv = *(const float4*)(Wenc + (size_t)(k0 + bkr) * FDIM + bn + bc4);
        __syncthreads();
        Asf[ac4 + 0][arow] = av.x; Asf[ac4 + 1][arow] = av.y;
        Asf[ac4 + 2][arow] = av.z; Asf[ac4 + 3][arow] = av.w;
        *(float4*)&Bsf[bkr][bc4] = bv;
        __syncthreads();
        #pragma unroll
        for (int kkk = 0; kkk < BKK; ++kkk) {
            *(float4*)&af[0] = *(const float4*)&Asf[kkk][ty * 8];
            *(float4*)&af[4] = *(const float4*)&Asf[kkk][ty * 8 + 4];
            *(float4*)&bf[0] = *(const float4*)&Bsf[kkk][tx * 8];
            *(float4*)&bf[4] = *(const float4*)&Bsf[kkk][tx * 8 + 4];
            #pragma unroll
            for (int i = 0; i < 8; ++i)
                #pragma unroll
                for (int j = 0; j < 8; ++j)
                    acc[i][j] = fmaf(af[i], bf[j], acc[i][j]);
        }
    }

    float4 be0 = *(const float4*)(benc + bn + tx * 8);
    float4 be1 = *(const float4*)(benc + bn + tx * 8 + 4);
    #pragma unroll
    for (int i = 0; i < 8; ++i) {
        size_t ro = (size_t)(bm + ty * 8 + i) * FDIM + bn + tx * 8;
        float4 o0 = make_float4(acc[i][0] + be0.x, acc[i][1] + be0.y,
                                acc[i][2] + be0.z, acc[i][3] + be0.w);
        float4 o1 = make_float4(acc[i][4] + be1.x, acc[i][5] + be1.y,
                                acc[i][6] + be1.z, acc[i][7] + be1.w);
        *(float4*)(lat + ro)     = o0;
        *(float4*)(lat + ro + 4) = o1;
    }
}

__global__ __launch_bounds__(256)
void topk_mask_decode(float* __restrict__ lat, const float* __restrict__ Wdec,
                      const float* __restrict__ bdec, const int* __restrict__ kptr,
                      float* __restrict__ xrec)
{
    const int row = blockIdx.x;
    const int tid = threadIdx.x;
    float* lrow = lat + (size_t)row * FDIM;
    int kk = *kptr;
    if (kk < 1) kk = 1;
    if (kk > CAP) kk = CAP;

    __shared__ uint32_t ckey[CAP];
    __shared__ uint32_t cidx[CAP];
    __shared__ float redf[256];
    __shared__ int   redi[256];
    __shared__ int   cc;

    float ss = 0.f;
    for (int i = tid * 4; i < FDIM; i += 1024) {
        float4 v = *(const float4*)(lrow + i);
        ss = fmaf(v.x, v.x, fmaf(v.y, v.y, fmaf(v.z, v.z, fmaf(v.w, v.w, ss))));
    }
    redf[tid] = ss;
    __syncthreads();
    for (int s = 128; s > 0; s >>= 1) { if (tid < s) redf[tid] += redf[tid + s]; __syncthreads(); }
    const float sigma = sqrtf(redf[0] / (float)FDIM);

    uint32_t ulo = 0u, uhi = 0xFFFFFFFFu;
    uint32_t ut = f2u(2.7f * sigma);
    int state = 0; uint32_t kthu = 0u; int cfound = 0;

    for (int it = 0; it < 72; ++it) {
        if (uhi - ulo <= 1u) { state = 2; kthu = uhi; break; }
        if (ut <= ulo) ut = ulo + 1u;
        if (ut >= uhi) ut = uhi - 1u;
        const float t = u2f(ut);
        __syncthreads();
        if (tid == 0) cc = 0;
        __syncthreads();
        for (int i = tid * 4; i < FDIM; i += 1024) {
            float4 v = *(const float4*)(lrow + i);
            float vv[4] = {v.x, v.y, v.z, v.w};
            #pragma unroll
            for (int j = 0; j < 4; ++j) {
                if (vv[j] > t) {
                    int p = atomicAdd(&cc, 1);
                    if (p < CAP) { ckey[p] = f2u(vv[j]); cidx[p] = (uint32_t)(i + j); }
                }
            }
        }
        __syncthreads();
        const int c = cc;
        if (c >= kk && c <= CAP) { state = 1; cfound = c; break; }
        if (c < kk) uhi = ut; else ulo = ut;
        ut = ulo + ((uhi - ulo) >> 1);
    }
    if (state == 0) { state = 2; kthu = uhi; }

    const int e0 = tid, e1 = tid + 256, e2 = tid + 512;

    if (state == 1) {
        for (int i = cfound + tid; i < CAP; i += 256) { ckey[i] = 0u; cidx[i] = 0u; }
        __syncthreads();
        for (int ksz = 2; ksz <= CAP; ksz <<= 1) {
            for (int j = ksz >> 1; j > 0; j >>= 1) {
                for (int i = tid; i < CAP; i += 256) {
                    const int ixj = i ^ j;
                    if (ixj > i) {
                        uint32_t ka = ckey[i], kb = ckey[ixj];
                        uint32_t ia = cidx[i], ib = cidx[ixj];
                        bool after = (ka < kb) || (ka == kb && ia > ib);
                        bool descBlock = ((i & ksz) == 0);
                        if (descBlock ? after : !after) {
                            ckey[i] = kb; ckey[ixj] = ka;
                            cidx[i] = ib; cidx[ixj] = ia;
                        }
                    }
                }
                __syncthreads();
            }
        }
        const float kthf = u2f(ckey[kk - 1]);

        int lm = 0;
        for (int j2 = tid; j2 < cfound; j2 += 256) lm += (u2f(ckey[j2]) >= kthf) ? 1 : 0;
        redi[tid] = lm;
        __syncthreads();
        for (int s = 128; s > 0; s >>= 1) { if (tid < s) redi[tid] += redi[tid + s]; __syncthreads(); }
        const int m = redi[0];

        const float4 z4 = make_float4(0.f, 0.f, 0.f, 0.f);
        for (int i = tid * 4; i < FDIM; i += 1024) *(float4*)(lrow + i) = z4;
        __syncthreads();
        for (int j2 = tid; j2 < m; j2 += 256) lrow[cidx[j2]] = u2f(ckey[j2]);

        float a0 = 0.f, a1 = 0.f, a2 = 0.f;
        for (int j2 = 0; j2 < m; ++j2) {
            const float v = u2f(ckey[j2]);
            const float* wr = Wdec + (size_t)cidx[j2] * EDIM;
            a0 = fmaf(v, wr[e0], a0);
            a1 = fmaf(v, wr[e1], a1);
            a2 = fmaf(v, wr[e2], a2);
        }
        xrec[(size_t)row * EDIM + e0] = a0 + bdec[e0];
        xrec[(size_t)row * EDIM + e1] = a1 + bdec[e1];
        xrec[(size_t)row * EDIM + e2] = a2 + bdec[e2];
    } else {
        const float kthf = u2f(kthu);
        float a0 = 0.f, a1 = 0.f, a2 = 0.f;
        for (int base = 0; base < FDIM; base += 512) {
            __syncthreads();
            if (tid == 0) cc = 0;
            __syncthreads();
            const int i = base + tid * 2;
            float2 v = *(const float2*)(lrow + i);
            float2 o;
            o.x = (v.x >= kthf) ? v.x : 0.f;
            o.y = (v.y >= kthf) ? v.y : 0.f;
            *(float2*)(lrow + i) = o;
            if (v.x >= kthf) { int p = atomicAdd(&cc, 1); ckey[p] = __float_as_uint(v.x); cidx[p] = (uint32_t)i; }
            if (v.y >= kthf) { int p = atomicAdd(&cc, 1); ckey[p] = __float_as_uint(v.y); cidx[p] = (uint32_t)(i + 1); }
            __syncthreads();
            const int c = cc;
            for (int j2 = 0; j2 < c; ++j2) {
                const float v2 = __uint_as_float(ckey[j2]);
                const float* wr = Wdec + (size_t)cidx[j2] * EDIM;
                a0 = fmaf(v2, wr[e0], a0);
                a1 = fmaf(v2, wr[e1], a1);
                a2 = fmaf(v2, wr[e2], a2);
            }
        }
        xrec[(size_t)row * EDIM + e0] = a0 + bdec[e0];
        xrec[(size_t)row * EDIM + e1] = a1 + bdec[e1];
        xrec[(size_t)row * EDIM + e2] = a2 + bdec[e2];
    }
}

// ============================================================
extern "C" void kernel_launch(void* const* d_in, const int* in_sizes, int n_in,
                              void* d_out, int out_size, void* d_ws, size_t ws_size,
                              hipStream_t stream) {
    const float* x    = (const float*)d_in[0];
    const float* Wenc = (const float*)d_in[1];
    const float* Wdec = (const float*)d_in[2];
    const float* benc = (const float*)d_in[3];
    const float* bdec = (const float*)d_in[4];
    const int*   kptr = (const int*)d_in[5];

    float* xrec = (float*)d_out;                          // (4096, 768)
    float* fm   = (float*)d_out + (size_t)BT_TOK * EDIM;  // (4096, 24576)

    const size_t szAi = (size_t)BT_TOK * EDIM;            //  3,145,728 (i8)
    const size_t szWi = (size_t)FDIM * EDIM;              // 18,874,368 (i8)
    const size_t szWT = (size_t)FDIM * EDIM * 4;          // 75,497,472 (f32)
    const size_t szSx = (size_t)BT_TOK * 4;
    const size_t szSw = (size_t)FDIM * 4;
    const size_t base = szAi + szWi + szWT + szSx + szSw;
    const size_t szCd = (size_t)NSEG * BT_TOK * SEGW * 4; // 100,663,296

    if (ws_size >= base) {
        unsigned char* Ai8 = (unsigned char*)d_ws;
        unsigned char* Wi8 = (unsigned char*)d_ws + szAi;
        float*         WTf = (float*)((char*)d_ws + szAi + szWi);
        float*         sxr = (float*)((char*)d_ws + szAi + szWi + szWT);
        float*         sw  = (float*)((char*)d_ws + szAi + szWi + szWT + szSx);
        uint32_t*      cnd = (uint32_t*)((char*)d_ws + base);

        build_A_i8<<<BT_TOK / 4, 256, 0, stream>>>(x, bdec, Ai8, sxr);
        build_WT<<<dim3(FDIM / TT, EDIM / TT), 256, 0, stream>>>(Wenc, WTf);
        quantW_i8<<<FDIM / 4, 256, 0, stream>>>(WTf, Wi8, sw);
        if (ws_size >= base + szCd) {
            encode_i8_cand<1><<<dim3(FDIM / GBN, BT_TOK / GBM), 256, 0, stream>>>(
                Ai8, Wi8, benc, sxr, sw, fm, cnd);
            topk2<1><<<BT_TOK, 256, 0, stream>>>(fm, xrec, x, WTf, Wenc, Wdec,
                                                 benc, bdec, kptr, cnd);
        } else {
            encode_i8_cand<0><<<dim3(FDIM / GBN, BT_TOK / GBM), 256, 0, stream>>>(
                Ai8, Wi8, benc, sxr, sw, fm, nullptr);
            topk2<0><<<BT_TOK, 256, 0, stream>>>(fm, xrec, x, WTf, Wenc, Wdec,
                                                 benc, bdec, kptr, nullptr);
        }
    } else {
        dim3 g1(FDIM / BN, BT_TOK / BM);
        encode_gemm<<<g1, 256, 0, stream>>>(x, Wenc, benc, bdec, fm);
        topk_mask_decode<<<BT_TOK, 256, 0, stream>>>(fm, Wdec, bdec, kptr, xrec);
    }
}